// Round 1
// baseline (1443.280 us; speedup 1.0000x reference)
//
#include <hip/hip_runtime.h>
#include <math.h>

// Model dims
#define S_ 87
#define B_ 8
#define D_ 5
#define T_ 30
#define H_ 64
#define G_ 192   // 3*H

__device__ __forceinline__ float sigmoidf_(float x){ return 1.0f/(1.0f+expf(-x)); }

__device__ __forceinline__ float warp_sum(float v){
  #pragma unroll
  for (int off=32; off>0; off>>=1) v += __shfl_xor(v, off, 64);
  return v;
}
__device__ __forceinline__ float warp_max(float v){
  #pragma unroll
  for (int off=32; off>0; off>>=1) v = fmaxf(v, __shfl_xor(v, off, 64));
  return v;
}

// ---------------------------------------------------------------------------
// Kernel 1: tweet input projection (the big GEMM)
// xi_t[s,d,b,t,g] = sum_k text[b,s,d,t,k]*Wih[s,g,k] + bih[s,g]
// Per (s,d): M=240 rows (b*30+t), N=192, K=512. Tiles 64x64, Kc=64.
// ---------------------------------------------------------------------------
__global__ __launch_bounds__(256) void k_tweet_proj(
    const float* __restrict__ text, const float* __restrict__ Wih,
    const float* __restrict__ bih, float* __restrict__ xi_t){
  __shared__ float As[64*68];   // transposed: As[k][m], row stride 68 (16B-aligned pad)
  __shared__ float Bs[64*68];   // Bs[k][n]
  const int tid = threadIdx.x;
  const int bx = blockIdx.x;              // 0..11
  const int mtile = bx & 3, ntile = bx >> 2;
  const int d = blockIdx.y, s = blockIdx.z;
  const int mbase = mtile*64, nbase = ntile*64;

  const int lsub = tid & 15;              // k-quad within chunk
  const int mrow = tid >> 4;              // 0..15

  const float* aptr[4]; bool aval[4];
  const float* bptr[4];
  #pragma unroll
  for (int mi=0; mi<4; ++mi){
    int m   = mrow + mi*16;
    int row = mbase + m;
    bool v  = row < 240;
    int rr  = v ? row : 0;
    int b   = rr/30, t = rr - b*30;
    aptr[mi] = text + (size_t)(b*13050 + s*150 + d*30 + t)*512 + lsub*4;
    aval[mi] = v;
    int g = nbase + m;
    bptr[mi] = Wih + (size_t)(s*192 + g)*512 + lsub*4;
  }
  const int ty4 = (tid>>4)*4, tx4 = (tid&15)*4;
  float acc[4][4] = {};

  for (int kc=0; kc<512; kc+=64){
    __syncthreads();
    #pragma unroll
    for (int mi=0; mi<4; ++mi){
      int m = mrow + mi*16;
      float4 av = make_float4(0.f,0.f,0.f,0.f);
      if (aval[mi]) av = *(const float4*)(aptr[mi] + kc);
      As[(lsub*4+0)*68 + m] = av.x;
      As[(lsub*4+1)*68 + m] = av.y;
      As[(lsub*4+2)*68 + m] = av.z;
      As[(lsub*4+3)*68 + m] = av.w;
      float4 bv = *(const float4*)(bptr[mi] + kc);
      Bs[(lsub*4+0)*68 + m] = bv.x;
      Bs[(lsub*4+1)*68 + m] = bv.y;
      Bs[(lsub*4+2)*68 + m] = bv.z;
      Bs[(lsub*4+3)*68 + m] = bv.w;
    }
    __syncthreads();
    #pragma unroll 8
    for (int kk=0; kk<64; ++kk){
      float4 a = *(const float4*)&As[kk*68 + ty4];
      float4 b = *(const float4*)&Bs[kk*68 + tx4];
      acc[0][0] += a.x*b.x; acc[0][1] += a.x*b.y; acc[0][2] += a.x*b.z; acc[0][3] += a.x*b.w;
      acc[1][0] += a.y*b.x; acc[1][1] += a.y*b.y; acc[1][2] += a.y*b.z; acc[1][3] += a.y*b.w;
      acc[2][0] += a.z*b.x; acc[2][1] += a.z*b.y; acc[2][2] += a.z*b.z; acc[2][3] += a.z*b.w;
      acc[3][0] += a.w*b.x; acc[3][1] += a.w*b.y; acc[3][2] += a.w*b.z; acc[3][3] += a.w*b.w;
    }
  }
  float4 bihv = *(const float4*)&bih[s*192 + nbase + tx4];
  #pragma unroll
  for (int i=0;i<4;++i){
    int row = mbase + ty4 + i;
    if (row < 240){
      float4 o;
      o.x = acc[i][0] + bihv.x; o.y = acc[i][1] + bihv.y;
      o.z = acc[i][2] + bihv.z; o.w = acc[i][3] + bihv.w;
      *(float4*)&xi_t[(size_t)((s*5+d)*240 + row)*192 + nbase + tx4] = o;
    }
  }
}

// ---------------------------------------------------------------------------
// Kernel 2: tweet GRU (30 steps) + Bahdanau attention, one block per (s,d)
// ---------------------------------------------------------------------------
__global__ __launch_bounds__(384) void k_tweet_gru(
    const float* __restrict__ xi_t, const float* __restrict__ Whh, const float* __restrict__ bhh,
    const float* __restrict__ W1, const float* __restrict__ b1,
    const float* __restrict__ W2, const float* __restrict__ b2,
    const float* __restrict__ V, const float* __restrict__ bV,
    float* __restrict__ full_t, float* __restrict__ news){
  __shared__ float sm[14336];
  float* h   = sm;          // 512
  float* gh  = sm + 512;    // 1536
  float* big = sm + 2048;   // 12288 (phase1: Whh^T [k][g])
  const int tid = threadIdx.x;
  const int bid = blockIdx.x;
  const int s = bid/5, d = bid - (bid/5)*5;

  // stage Whh transposed: Wt[k*192+g] = Whh[s,g,k]
  for (int idx = tid; idx < 192*16; idx += 384){
    int g = idx >> 4, kq = idx & 15;
    float4 w = *(const float4*)&Whh[(size_t)(s*192+g)*64 + kq*4];
    big[(kq*4+0)*192 + g] = w.x;
    big[(kq*4+1)*192 + g] = w.y;
    big[(kq*4+2)*192 + g] = w.z;
    big[(kq*4+3)*192 + g] = w.w;
  }
  for (int idx = tid; idx < 512; idx += 384) h[idx] = 0.f;
  const int b = tid/48, gq = tid - b*48;       // b:0..7, gq:0..47 (4 g's each)
  float4 bh4 = *(const float4*)&bhh[s*192 + gq*4];
  __syncthreads();

  const size_t sd240 = (size_t)(s*5+d)*240;
  for (int t30 = 0; t30 < 30; ++t30){
    float4 acc = bh4;
    #pragma unroll 16
    for (int k=0;k<64;++k){
      float hk = h[b*64+k];
      float4 w = *(const float4*)&big[k*192 + gq*4];
      acc.x += hk*w.x; acc.y += hk*w.y; acc.z += hk*w.z; acc.w += hk*w.w;
    }
    *(float4*)&gh[b*192+gq*4] = acc;
    __syncthreads();
    for (int idx = tid; idx < 512; idx += 384){
      int bb = idx>>6, j = idx&63;
      size_t rbase = sd240 + bb*30 + t30;
      const float* xr = xi_t + rbase*192 + j;
      float r = sigmoidf_(xr[0]   + gh[bb*192+j]);
      float z = sigmoidf_(xr[64]  + gh[bb*192+64+j]);
      float n = tanhf(   xr[128] + r*gh[bb*192+128+j]);
      float hv = h[bb*64+j];
      float hn = (1.f - z)*n + z*hv;
      h[bb*64+j] = hn;
      full_t[rbase*64 + j] = hn;
    }
    __syncthreads();
  }

  // ---- attention over T=30 ----
  float* q   = sm + 512;    // reuse gh region
  float* W2t = big;         // 4096
  float* Vs  = big + 4096;  // 64
  float* b2s = big + 4160;  // 64
  float* sc  = big + 4224;  // 240
  float* wsm = big + 4464;  // 240
  for (int idx = tid; idx < 512; idx += 384){
    int bb = idx>>6, j = idx&63;
    float acc = b1[s*64+j];
    const float* wr = W1 + (size_t)(s*64+j)*64;
    #pragma unroll
    for (int kq=0;kq<16;++kq){
      float4 w = *(const float4*)(wr + kq*4);
      acc += h[bb*64+kq*4+0]*w.x + h[bb*64+kq*4+1]*w.y
           + h[bb*64+kq*4+2]*w.z + h[bb*64+kq*4+3]*w.w;
    }
    q[idx] = acc;
  }
  for (int idx = tid; idx < 64*16; idx += 384){
    int j = idx>>4, kq = idx&15;
    float4 w = *(const float4*)&W2[(size_t)(s*64+j)*64 + kq*4];
    W2t[(kq*4+0)*64 + j] = w.x;
    W2t[(kq*4+1)*64 + j] = w.y;
    W2t[(kq*4+2)*64 + j] = w.z;
    W2t[(kq*4+3)*64 + j] = w.w;
  }
  for (int idx = tid; idx < 64; idx += 384){ Vs[idx] = V[s*64+idx]; b2s[idx] = b2[s*64+idx]; }
  __syncthreads();
  const int w = tid>>6, lane = tid&63;
  const float bVs = bV[s];
  for (int i=0;i<40;++i){
    int pair = w*40+i;                       // == bb*30+tt
    int bb = pair/30, tt = pair - bb*30;
    const float* f = full_t + (sd240 + bb*30 + tt)*64;
    float v = f[lane];
    float u = q[bb*64+lane] + b2s[lane];
    #pragma unroll 16
    for (int k=0;k<64;++k) u += W2t[k*64+lane]*__shfl(v, k, 64);
    float p = warp_sum(tanhf(u)*Vs[lane]);
    if (lane==0) sc[pair] = p + bVs;
  }
  __syncthreads();
  if (tid < 8){
    float mx = -1e30f;
    for (int tt=0;tt<30;++tt) mx = fmaxf(mx, sc[tid*30+tt]);
    float ssum = 0.f;
    for (int tt=0;tt<30;++tt){ float e = expf(sc[tid*30+tt]-mx); wsm[tid*30+tt] = e; ssum += e; }
    float inv = 1.f/ssum;
    for (int tt=0;tt<30;++tt) wsm[tid*30+tt] *= inv;
  }
  __syncthreads();
  for (int idx = tid; idx < 512; idx += 384){
    int bb = idx>>6, j = idx&63;
    float acc = 0.f;
    for (int tt=0;tt<30;++tt) acc += wsm[bb*30+tt]*full_t[(sd240 + bb*30+tt)*64 + j];
    news[(size_t)(s*5+d)*512 + bb*64 + j] = acc;   // news[s][d][b][j]
  }
}

// ---------------------------------------------------------------------------
// Shared helper: 5-step GRU (xi precomputed in LDS, index [b*5+d][192]) + attention
// 256 threads. full[2560], h[512], gh[1536], scratch>=4816 floats.
// ---------------------------------------------------------------------------
__device__ void gru5_attn(
    const int s, const int tid,
    float* full, float* h, const float* xi, float* gh, float* scratch,
    const float* __restrict__ Whh, const float* __restrict__ bhh,
    const float* __restrict__ W1, const float* __restrict__ b1,
    const float* __restrict__ W2, const float* __restrict__ b2,
    const float* __restrict__ V, const float* __restrict__ bV,
    float* __restrict__ outvec){
  const int b8 = tid>>5, g0 = tid&31;
  for (int dd=0; dd<5; ++dd){
    for (int r_=0;r_<6;++r_){
      int g = r_*32+g0;
      float acc = bhh[s*192+g];
      const float* wr = Whh + (size_t)(s*192+g)*64;
      #pragma unroll
      for (int kq=0;kq<16;++kq){
        float4 w = *(const float4*)(wr+kq*4);
        acc += h[b8*64+kq*4+0]*w.x + h[b8*64+kq*4+1]*w.y
             + h[b8*64+kq*4+2]*w.z + h[b8*64+kq*4+3]*w.w;
      }
      gh[b8*192+g] = acc;
    }
    __syncthreads();
    for (int idx=tid; idx<512; idx+=256){
      int bb = idx>>6, j = idx&63;
      const float* xr = xi + (bb*5+dd)*192;
      float r = sigmoidf_(xr[j]     + gh[bb*192+j]);
      float z = sigmoidf_(xr[64+j]  + gh[bb*192+64+j]);
      float n = tanhf(   xr[128+j] + r*gh[bb*192+128+j]);
      float hv = h[bb*64+j];
      float hn = (1.f-z)*n + z*hv;
      h[bb*64+j] = hn;
      full[(bb*5+dd)*64 + j] = hn;
    }
    __syncthreads();
  }
  // attention over D=5
  float* q   = scratch;          // 512
  float* W2t = scratch + 512;    // 4096
  float* Vs  = scratch + 4608;   // 64
  float* b2s = scratch + 4672;   // 64
  float* sc  = scratch + 4736;   // 40
  float* wsm = scratch + 4776;   // 40
  for (int idx=tid; idx<512; idx+=256){
    int bb = idx>>6, j = idx&63;
    float acc = b1[s*64+j];
    const float* wr = W1 + (size_t)(s*64+j)*64;
    #pragma unroll
    for (int kq=0;kq<16;++kq){
      float4 w = *(const float4*)(wr+kq*4);
      acc += h[bb*64+kq*4+0]*w.x + h[bb*64+kq*4+1]*w.y
           + h[bb*64+kq*4+2]*w.z + h[bb*64+kq*4+3]*w.w;
    }
    q[idx] = acc;
  }
  for (int idx=tid; idx<1024; idx+=256){
    int j = idx>>4, kq = idx&15;
    float4 w = *(const float4*)&W2[(size_t)(s*64+j)*64 + kq*4];
    W2t[(kq*4+0)*64+j]=w.x; W2t[(kq*4+1)*64+j]=w.y;
    W2t[(kq*4+2)*64+j]=w.z; W2t[(kq*4+3)*64+j]=w.w;
  }
  for (int idx=tid; idx<64; idx+=256){ Vs[idx]=V[s*64+idx]; b2s[idx]=b2[s*64+idx]; }
  __syncthreads();
  const int w = tid>>6, lane = tid&63;
  for (int i=0;i<10;++i){
    int pair = w*10+i;                  // == bb*5+dd
    int bb = pair/5, dd = pair - bb*5;
    float u = q[bb*64+lane] + b2s[lane];
    #pragma unroll 16
    for (int k=0;k<64;++k) u += W2t[k*64+lane]*full[(bb*5+dd)*64+k];
    float p = warp_sum(tanhf(u)*Vs[lane]);
    if (lane==0) sc[pair] = p + bV[s];
  }
  __syncthreads();
  if (tid<8){
    float mx=-1e30f; for (int dd=0;dd<5;++dd) mx=fmaxf(mx, sc[tid*5+dd]);
    float ssum=0.f;
    for (int dd=0;dd<5;++dd){ float e=expf(sc[tid*5+dd]-mx); wsm[tid*5+dd]=e; ssum+=e; }
    float inv=1.f/ssum;
    for (int dd=0;dd<5;++dd) wsm[tid*5+dd]*=inv;
  }
  __syncthreads();
  for (int idx=tid; idx<512; idx+=256){
    int bb=idx>>6, j=idx&63;
    float acc=0.f;
    for (int dd=0;dd<5;++dd) acc += wsm[bb*5+dd]*full[(bb*5+dd)*64+j];
    outvec[(size_t)(s*8+bb)*64 + j] = acc;
  }
}

// ---------------------------------------------------------------------------
// Kernel 3: price GRU (din=3) + attention, per s
// ---------------------------------------------------------------------------
__global__ __launch_bounds__(256) void k_price(
    const float* __restrict__ price,
    const float* __restrict__ Wih, const float* __restrict__ Whh,
    const float* __restrict__ bih, const float* __restrict__ bhh,
    const float* __restrict__ W1, const float* __restrict__ b1,
    const float* __restrict__ W2, const float* __restrict__ b2,
    const float* __restrict__ V, const float* __restrict__ bV,
    float* __restrict__ x_price){
  __shared__ float sm[13000];
  float* full = sm;          // 2560
  float* h    = sm + 2560;   // 512
  float* reg  = sm + 3072;
  float* pr = reg;           // 120
  float* xi = reg + 128;     // 7680
  float* gh = reg + 128 + 7680; // 1536
  const int tid = threadIdx.x;
  const int s = blockIdx.x;
  for (int idx=tid; idx<120; idx+=256){
    int bb = idx/15, rem = idx - bb*15; int dd = rem/3, k = rem - dd*3;
    pr[idx] = price[(size_t)((bb*87+s)*5+dd)*3 + k];
  }
  for (int idx=tid; idx<512; idx+=256) h[idx]=0.f;
  __syncthreads();
  for (int idx=tid; idx<7680; idx+=256){
    int bd = idx/192, g = idx - bd*192;
    const float* wr = Wih + (size_t)(s*192+g)*3;
    xi[idx] = bih[s*192+g] + pr[bd*3]*wr[0] + pr[bd*3+1]*wr[1] + pr[bd*3+2]*wr[2];
  }
  __syncthreads();
  gru5_attn(s, tid, full, h, xi, gh, reg, Whh, bhh, W1, b1, W2, b2, V, bV, x_price);
}

// ---------------------------------------------------------------------------
// Kernel 4: day-level GRU over news (din=64) + attention, per s
// ---------------------------------------------------------------------------
__global__ __launch_bounds__(256) void k_day(
    const float* __restrict__ news,
    const float* __restrict__ Wih, const float* __restrict__ Whh,
    const float* __restrict__ bih, const float* __restrict__ bhh,
    const float* __restrict__ W1, const float* __restrict__ b1,
    const float* __restrict__ W2, const float* __restrict__ b2,
    const float* __restrict__ V, const float* __restrict__ bV,
    float* __restrict__ text_vec){
  __shared__ float sm[15000];
  float* full = sm;          // 2560
  float* h    = sm + 2560;   // 512
  float* reg  = sm + 3072;
  float* nw = reg;               // 2560  (news[s][d][b][k])
  float* xi = reg + 2560;        // 7680
  float* gh = reg + 2560 + 7680; // 1536
  const int tid = threadIdx.x;
  const int s = blockIdx.x;
  for (int idx=tid; idx<2560; idx+=256) nw[idx] = news[(size_t)s*2560 + idx];
  for (int idx=tid; idx<512; idx+=256) h[idx]=0.f;
  __syncthreads();
  for (int idx=tid; idx<7680; idx+=256){
    int bd = idx/192, g = idx - bd*192;
    int bb = bd/5, dd = bd - bb*5;
    const float* wr = Wih + (size_t)(s*192+g)*64;
    const float* xr = nw + (dd*8+bb)*64;   // x[b,d,:] = news[s,d,b,:]
    float acc = bih[s*192+g];
    #pragma unroll
    for (int kq=0;kq<16;++kq){
      float4 w = *(const float4*)(wr+kq*4);
      acc += xr[kq*4+0]*w.x + xr[kq*4+1]*w.y + xr[kq*4+2]*w.z + xr[kq*4+3]*w.w;
    }
    xi[idx]=acc;
  }
  __syncthreads();
  gru5_attn(s, tid, full, h, xi, gh, reg, Whh, bhh, W1, b1, W2, b2, V, bV, text_vec);
}

// ---------------------------------------------------------------------------
// Kernel 5: bilinear fusion. out[b,s,k] = tanh(text^T W_k price + b_k)
// grid (4, 87): block covers 16 k's; W read exactly once (91 MB, mem-bound)
// ---------------------------------------------------------------------------
__global__ __launch_bounds__(256) void k_bilinear(
    const float* __restrict__ text_vec, const float* __restrict__ x_price,
    const float* __restrict__ bilW, const float* __restrict__ bilb,
    float* __restrict__ ft_vec){
  __shared__ float tv[512], pv[512];
  const int tid = threadIdx.x;
  const int kb = blockIdx.x, s = blockIdx.y;
  for (int idx=tid; idx<512; idx+=256){ tv[idx]=text_vec[s*512+idx]; pv[idx]=x_price[s*512+idx]; }
  __syncthreads();
  const int w = tid>>6, lane = tid&63;
  const int j = (lane&15)*4;
  const int ib = lane>>4;
  float4 pj[8];
  #pragma unroll
  for (int bb=0;bb<8;++bb) pj[bb] = *(const float4*)&pv[bb*64+j];
  for (int kk=0;kk<4;++kk){
    int k = kb*16 + w*4 + kk;
    const float* base = bilW + (size_t)(s*64+k)*4096;
    float acc[8] = {0,0,0,0,0,0,0,0};
    for (int it=0; it<16; ++it){
      float4 wv = *(const float4*)(base + it*256 + lane*4);
      int i = it*4 + ib;
      #pragma unroll
      for (int bb=0;bb<8;++bb){
        float partial = wv.x*pj[bb].x + wv.y*pj[bb].y + wv.z*pj[bb].z + wv.w*pj[bb].w;
        acc[bb] += partial * tv[bb*64+i];
      }
    }
    #pragma unroll
    for (int bb=0;bb<8;++bb){
      float tot = warp_sum(acc[bb]);
      if (lane==0) ft_vec[(size_t)(bb*87+s)*64 + k] = tanhf(tot + bilb[s*64+k]);
    }
  }
}

// ---------------------------------------------------------------------------
// Kernel 6: GAT head projections Wh = ft_vec @ gat_W[h], plus a1/a2
// ---------------------------------------------------------------------------
__global__ __launch_bounds__(256) void k_gat_wh(
    const float* __restrict__ ft_vec, const float* __restrict__ gatW,
    const float* __restrict__ gata,
    float* __restrict__ Wh_g, float* __restrict__ a1h, float* __restrict__ a2h){
  __shared__ float ftb[5568];
  __shared__ float Ws[4096];
  const int tid = threadIdx.x;
  const int hd = blockIdx.x>>3, b = blockIdx.x&7;
  for (int idx=tid; idx<5568; idx+=256) ftb[idx] = ft_vec[(size_t)b*5568 + idx];
  for (int idx=tid; idx<4096; idx+=256) Ws[idx]  = gatW[(size_t)hd*4096 + idx];
  __syncthreads();
  const int f = tid&63, sq = tid>>6;
  const float af1 = gata[hd*128 + f], af2 = gata[hd*128 + 64 + f];
  for (int p=0;p<22;++p){
    int ss = p*4 + sq;
    if (ss < 87){
      float acc = 0.f;
      #pragma unroll 16
      for (int k=0;k<64;++k) acc += ftb[ss*64+k]*Ws[k*64+f];
      Wh_g[(size_t)((hd*8+b)*87 + ss)*64 + f] = acc;
      float p1 = warp_sum(acc*af1);
      float p2 = warp_sum(acc*af2);
      if (f==0){ a1h[(hd*8+b)*87 + ss] = p1; a2h[(hd*8+b)*87 + ss] = p2; }
    }
  }
}

// ---------------------------------------------------------------------------
// Kernel 7: GAT attention per (head,b): softmax(masked leakyrelu) @ Wh, elu
// ---------------------------------------------------------------------------
__global__ __launch_bounds__(256) void k_gat_att(
    const float* __restrict__ Wh_g, const float* __restrict__ a1h,
    const float* __restrict__ a2h, const float* __restrict__ adj,
    float* __restrict__ xg){
  __shared__ float whs[5568];
  __shared__ float a1s[96], a2s[96];
  __shared__ float adjs[7569];
  __shared__ float attw[4*128];
  const int tid = threadIdx.x;
  const int hd = blockIdx.x>>3, b = blockIdx.x&7;
  const int hb = hd*8+b;
  for (int idx=tid; idx<5568; idx+=256) whs[idx] = Wh_g[(size_t)hb*5568 + idx];
  for (int idx=tid; idx<87;   idx+=256){ a1s[idx]=a1h[hb*87+idx]; a2s[idx]=a2h[hb*87+idx]; }
  for (int idx=tid; idx<7569; idx+=256) adjs[idx]=adj[idx];
  __syncthreads();
  const int w = tid>>6, lane = tid&63;
  for (int i=0;i<22;++i){
    int n = w + 4*i;
    if (n < 87){
      float a1n = a1s[n];
      float x1 = a1n + a2s[lane];
      float e1 = (adjs[n*87+lane] > 0.f) ? (x1>0.f? x1 : 0.2f*x1) : -9e15f;
      float e2 = -INFINITY;
      if (lane < 23){
        float x2 = a1n + a2s[64+lane];
        e2 = (adjs[n*87+64+lane] > 0.f) ? (x2>0.f? x2 : 0.2f*x2) : -9e15f;
      }
      float mx  = warp_max(fmaxf(e1,e2));
      float ex1 = expf(e1-mx);
      float ex2 = (lane<23) ? expf(e2-mx) : 0.f;
      float inv = 1.f/warp_sum(ex1+ex2);
      attw[w*128+lane] = ex1*inv;
      if (lane<23) attw[w*128+64+lane] = ex2*inv;
      float o = 0.f;
      for (int m=0;m<87;++m) o += attw[w*128+m]*whs[m*64+lane];
      float val = (o>0.f) ? o : expm1f(o);
      xg[(size_t)(b*87+n)*512 + hd*64 + lane] = val;
    }
  }
}

// ---------------------------------------------------------------------------
// Kernel 8: second GAT layer (F'=2) + out_1 + expected_price + assemble
// ---------------------------------------------------------------------------
__global__ __launch_bounds__(256) void k_final(
    const float* __restrict__ xg, const float* __restrict__ ft_vec,
    const float* __restrict__ outW, const float* __restrict__ outa,
    const float* __restrict__ lxW, const float* __restrict__ lxb,
    const float* __restrict__ lpW, const float* __restrict__ lpb,
    const float* __restrict__ adj, float* __restrict__ out){
  __shared__ float whs2[176];
  __shared__ float a1s[96], a2s[96];
  const int tid = threadIdx.x;
  const int b = blockIdx.x;
  for (int idx=tid; idx<174; idx+=256){
    int ss = idx>>1, c = idx&1;
    const float* xr = xg + (size_t)(b*87+ss)*512;
    float acc = 0.f;
    for (int k=0;k<512;++k) acc += xr[k]*outW[k*2+c];
    whs2[idx] = acc;
  }
  __syncthreads();
  for (int idx=tid; idx<87; idx+=256){
    a1s[idx] = whs2[idx*2]*outa[0] + whs2[idx*2+1]*outa[1];
    a2s[idx] = whs2[idx*2]*outa[2] + whs2[idx*2+1]*outa[3];
  }
  __syncthreads();
  const int w = tid>>6, lane = tid&63;
  for (int i=0;i<22;++i){
    int n = w + 4*i;
    if (n<87){
      float a1n = a1s[n];
      float x1 = a1n + a2s[lane];
      float e1 = (adj[n*87+lane]>0.f) ? (x1>0.f?x1:0.2f*x1) : -9e15f;
      float e2 = -INFINITY;
      if (lane<23){
        float x2 = a1n + a2s[64+lane];
        e2 = (adj[n*87+64+lane]>0.f) ? (x2>0.f?x2:0.2f*x2) : -9e15f;
      }
      float mx  = warp_max(fmaxf(e1,e2));
      float ex1 = expf(e1-mx);
      float ex2 = (lane<23)?expf(e2-mx):0.f;
      float inv = 1.f/warp_sum(ex1+ex2);
      float at1 = ex1*inv, at2 = ex2*inv;
      float p0 = at1*whs2[lane*2];
      float p1 = at1*whs2[lane*2+1];
      if (lane<23){ p0 += at2*whs2[(64+lane)*2]; p1 += at2*whs2[(64+lane)*2+1]; }
      float s0 = warp_sum(p0);
      float s1 = warp_sum(p1);
      float ftv = ft_vec[(size_t)(b*87+n)*64 + lane];
      float d0 = warp_sum(ftv*lxW[lane]);
      float d1 = warp_sum(ftv*lxW[64+lane]);
      float dp = warp_sum(ftv*lpW[lane]);
      if (lane==0){
        float ep  = tanhf(dp + lpb[0])*0.01f;
        float o10 = tanhf(d0 + lxb[0]);
        float o11 = tanhf(d1 + lxb[1]);
        float g0 = (s0>0.f)?s0:expm1f(s0);
        float g1 = (s1>0.f)?s1:expm1f(s1);
        float* op = out + (size_t)(b*87+n)*3;
        op[0] = ep; op[1] = g0 + o10; op[2] = g1 + o11;
      }
    }
  }
}

// ---------------------------------------------------------------------------
extern "C" void kernel_launch(void* const* d_in, const int* in_sizes, int n_in,
                              void* d_out, int out_size, void* d_ws, size_t ws_size,
                              hipStream_t stream){
  const float* text      = (const float*)d_in[0];
  const float* price     = (const float*)d_in[1];
  const float* adj       = (const float*)d_in[2];
  const float* grup_Wih  = (const float*)d_in[4];
  const float* grup_Whh  = (const float*)d_in[5];
  const float* grup_bih  = (const float*)d_in[6];
  const float* grup_bhh  = (const float*)d_in[7];
  const float* tgru_Wih  = (const float*)d_in[8];
  const float* tgru_Whh  = (const float*)d_in[9];
  const float* tgru_bih  = (const float*)d_in[10];
  const float* tgru_bhh  = (const float*)d_in[11];
  const float* grut_Wih  = (const float*)d_in[12];
  const float* grut_Whh  = (const float*)d_in[13];
  const float* grut_bih  = (const float*)d_in[14];
  const float* grut_bhh  = (const float*)d_in[15];
  const float* attnp_W1  = (const float*)d_in[16];
  const float* attnp_b1  = (const float*)d_in[17];
  const float* attnp_W2  = (const float*)d_in[18];
  const float* attnp_b2  = (const float*)d_in[19];
  const float* attnp_V   = (const float*)d_in[20];
  const float* attnp_bV  = (const float*)d_in[21];
  const float* attw_W1   = (const float*)d_in[22];
  const float* attw_b1   = (const float*)d_in[23];
  const float* attw_W2   = (const float*)d_in[24];
  const float* attw_b2   = (const float*)d_in[25];
  const float* attw_V    = (const float*)d_in[26];
  const float* attw_bV   = (const float*)d_in[27];
  const float* attnt_W1  = (const float*)d_in[28];
  const float* attnt_b1  = (const float*)d_in[29];
  const float* attnt_W2  = (const float*)d_in[30];
  const float* attnt_b2  = (const float*)d_in[31];
  const float* attnt_V   = (const float*)d_in[32];
  const float* attnt_bV  = (const float*)d_in[33];
  const float* bil_W     = (const float*)d_in[34];
  const float* bil_b     = (const float*)d_in[35];
  const float* lx_W      = (const float*)d_in[36];
  const float* lx_b      = (const float*)d_in[37];
  const float* lp_W      = (const float*)d_in[38];
  const float* lp_b      = (const float*)d_in[39];
  const float* gat_W     = (const float*)d_in[40];
  const float* gat_a     = (const float*)d_in[41];
  const float* out_W     = (const float*)d_in[42];
  const float* out_a     = (const float*)d_in[43];

  // workspace layout (floats); total 30,301,056 floats = 121.3 MB
  float* ws       = (float*)d_ws;
  float* xi_t     = ws;                      // 20,044,800
  float* full_t   = xi_t   + 20044800;       //  6,681,600
  float* news     = full_t + 6681600;        //    222,720
  float* x_price  = news   + 222720;         //     44,544
  float* text_vec = x_price + 44544;         //     44,544
  float* ft_vec   = text_vec + 44544;        //     44,544
  float* Wh_g     = ft_vec + 44544;          //  2,850,816
  float* a1h      = Wh_g   + 2850816;        //      5,568
  float* a2h      = a1h    + 5568;           //      5,568
  float* xg       = a2h    + 5568;           //    356,352

  k_tweet_proj<<<dim3(12,5,87),256,0,stream>>>(text, tgru_Wih, tgru_bih, xi_t);
  k_tweet_gru<<<435,384,0,stream>>>(xi_t, tgru_Whh, tgru_bhh,
      attw_W1, attw_b1, attw_W2, attw_b2, attw_V, attw_bV, full_t, news);
  k_price<<<87,256,0,stream>>>(price, grup_Wih, grup_Whh, grup_bih, grup_bhh,
      attnp_W1, attnp_b1, attnp_W2, attnp_b2, attnp_V, attnp_bV, x_price);
  k_day<<<87,256,0,stream>>>(news, grut_Wih, grut_Whh, grut_bih, grut_bhh,
      attnt_W1, attnt_b1, attnt_W2, attnt_b2, attnt_V, attnt_bV, text_vec);
  k_bilinear<<<dim3(4,87),256,0,stream>>>(text_vec, x_price, bil_W, bil_b, ft_vec);
  k_gat_wh<<<64,256,0,stream>>>(ft_vec, gat_W, gat_a, Wh_g, a1h, a2h);
  k_gat_att<<<64,256,0,stream>>>(Wh_g, a1h, a2h, adj, xg);
  k_final<<<8,256,0,stream>>>(xg, ft_vec, out_W, out_a, lx_W, lx_b, lp_W, lp_b,
      adj, (float*)d_out);
}

// Round 2
// 1133.645 us; speedup vs baseline: 1.2731x; 1.2731x over previous
//
#include <hip/hip_runtime.h>
#include <math.h>

// Model dims: S=87, B=8, D=5, T=30, H=64, G=192, K_text=512

typedef short s16x8 __attribute__((ext_vector_type(8)));
typedef float f32x4 __attribute__((ext_vector_type(4)));

__device__ __forceinline__ float sigmoidf_(float x){ return 1.0f/(1.0f+expf(-x)); }

__device__ __forceinline__ float warp_sum(float v){
  #pragma unroll
  for (int off=32; off>0; off>>=1) v += __shfl_xor(v, off, 64);
  return v;
}
__device__ __forceinline__ float warp_max(float v){
  #pragma unroll
  for (int off=32; off>0; off>>=1) v = fmaxf(v, __shfl_xor(v, off, 64));
  return v;
}

// split fp32 -> hi bf16 (round-half-up) + lo bf16 capturing residual (~2^-16 rel)
__device__ __forceinline__ void split_bf16(float x, unsigned short& hi, unsigned short& lo){
  unsigned u = __float_as_uint(x);
  unsigned r = u + 0x8000u;
  hi = (unsigned short)(r >> 16);
  float hif = __uint_as_float(r & 0xffff0000u);
  float l = x - hif;
  unsigned ul = __float_as_uint(l) + 0x8000u;
  lo = (unsigned short)(ul >> 16);
}

union U8 { unsigned short u[8]; s16x8 v; };

// ---------------------------------------------------------------------------
// Kernel 1: tweet input projection via split-bf16 MFMA.
// xi_t[s,d,row,g] = sum_k text[b,s,d,t,k]*Wih[s,g,k] + bih[s,g], row=b*30+t
// Per block: M=80 (mb of 3), N=192, K=512 in 16 chunks of 32.
// LDS staged in MFMA-fragment order: lane-contiguous 16B -> conflict-free.
// ---------------------------------------------------------------------------
__global__ __launch_bounds__(256) void k_tweet_proj(
    const float* __restrict__ text, const float* __restrict__ Wih,
    const float* __restrict__ bih, float* __restrict__ xi_t){
  __shared__ short lds[17408];   // Ah[2560] Al[2560] Bh[6144] Bl[6144] = 34816 B
  const int tid = threadIdx.x;
  const int mb = blockIdx.x, d = blockIdx.y, s = blockIdx.z;
  const int lane = tid & 63, w = tid >> 6, quad = lane >> 4;

  // precompute staging chunks (1088 = 320 A + 768 B chunks of 8 elems)
  const float* srcp[5]; int dsth[5]; int lodv[5]; int nch = 0;
  #pragma unroll
  for (int i=0;i<5;++i){
    int idx = tid + i*256;
    if (idx < 1088){
      if (idx < 320){
        int r = idx>>2, kc8 = idx&3;
        int row = mb*80 + r;
        int b = row/30, t = row - b*30;
        srcp[nch] = text + (size_t)(b*13050 + s*150 + d*30 + t)*512 + kc8*8;
        dsth[nch] = ((r>>4)*64 + ((r&15)|(kc8<<4)))*8;
        lodv[nch] = 2560;
      } else {
        int c = idx - 320;
        int g = c>>2, kc8 = c&3;
        srcp[nch] = Wih + (size_t)(s*192+g)*512 + kc8*8;
        dsth[nch] = 5120 + ((g>>4)*64 + ((g&15)|(kc8<<4)))*8;
        lodv[nch] = 6144;
      }
      ++nch;
    }
  }

  f32x4 acc[5][3] = {};

  for (int kc=0; kc<16; ++kc){
    __syncthreads();
    for (int i=0;i<nch;++i){
      const float* sp = srcp[i] + kc*32;
      float4 x0 = *(const float4*)sp;
      float4 x1 = *(const float4*)(sp+4);
      float xs[8] = {x0.x,x0.y,x0.z,x0.w,x1.x,x1.y,x1.z,x1.w};
      U8 hv, lv;
      #pragma unroll
      for (int j=0;j<8;++j) split_bf16(xs[j], hv.u[j], lv.u[j]);
      *(s16x8*)&lds[dsth[i]] = hv.v;
      *(s16x8*)&lds[dsth[i]+lodv[i]] = lv.v;
    }
    __syncthreads();
    s16x8 ah[5], al[5], bh[3], bl[3];
    #pragma unroll
    for (int mt=0;mt<5;++mt){
      ah[mt] = *(const s16x8*)&lds[(mt*64+lane)*8];
      al[mt] = *(const s16x8*)&lds[2560+(mt*64+lane)*8];
    }
    #pragma unroll
    for (int nl=0;nl<3;++nl){
      int nt = w*3+nl;
      bh[nl] = *(const s16x8*)&lds[5120+(nt*64+lane)*8];
      bl[nl] = *(const s16x8*)&lds[11264+(nt*64+lane)*8];
    }
    #pragma unroll
    for (int mt=0;mt<5;++mt){
      #pragma unroll
      for (int nl=0;nl<3;++nl){
        acc[mt][nl] = __builtin_amdgcn_mfma_f32_16x16x32_bf16(ah[mt], bh[nl], acc[mt][nl], 0,0,0);
        acc[mt][nl] = __builtin_amdgcn_mfma_f32_16x16x32_bf16(ah[mt], bl[nl], acc[mt][nl], 0,0,0);
        acc[mt][nl] = __builtin_amdgcn_mfma_f32_16x16x32_bf16(al[mt], bh[nl], acc[mt][nl], 0,0,0);
      }
    }
  }

  // epilogue: C/D layout col=lane&15, row=quad*4+reg  [verified m89/m91]
  const size_t obase = (size_t)(s*5+d)*240;
  #pragma unroll
  for (int nl=0;nl<3;++nl){
    int g = (w*3+nl)*16 + (lane&15);
    float bias = bih[s*192+g];
    #pragma unroll
    for (int mt=0;mt<5;++mt){
      #pragma unroll
      for (int reg=0;reg<4;++reg){
        int row = mb*80 + mt*16 + quad*4 + reg;
        xi_t[(obase+row)*192 + g] = acc[mt][nl][reg] + bias;
      }
    }
  }
}

// ---------------------------------------------------------------------------
// Kernel 2: tweet GRU (30 steps), one block per (s,d); conflict-free layouts:
//   Wt[k][g] reads are 8 distinct addrs/wave (broadcast), h padded stride 68.
// Epilogue computes q[s,d,b,:] = W1 h_last + b1 for the attention kernel.
// ---------------------------------------------------------------------------
__global__ __launch_bounds__(384) void k_gru30(
    const float* __restrict__ xi_t, const float* __restrict__ Whh, const float* __restrict__ bhh,
    const float* __restrict__ W1, const float* __restrict__ b1,
    float* __restrict__ full_t, float* __restrict__ q){
  __shared__ float sm[14400];
  float* Wt = sm;          // 12288: Wt[k*192+g] = Whh[s,g,k]
  float* h  = sm + 12288;  // 8*68
  float* gh = sm + 12832;  // 8*196
  const int tid = threadIdx.x;
  const int bid = blockIdx.x;
  const int s = bid/5;
  for (int idx = tid; idx < 3072; idx += 384){
    int g = idx >> 4, kq = idx & 15;
    float4 wv = *(const float4*)&Whh[(size_t)(s*192+g)*64 + kq*4];
    Wt[(kq*4+0)*192 + g] = wv.x;
    Wt[(kq*4+1)*192 + g] = wv.y;
    Wt[(kq*4+2)*192 + g] = wv.z;
    Wt[(kq*4+3)*192 + g] = wv.w;
  }
  for (int idx = tid; idx < 544; idx += 384) h[idx] = 0.f;
  const int gq = tid>>3, b = tid&7;        // gq 0..47, b 0..7
  float4 bh4 = *(const float4*)&bhh[s*192 + gq*4];
  __syncthreads();

  const size_t sd240 = (size_t)bid*240;
  for (int t=0; t<30; ++t){
    float4 acc = bh4;
    #pragma unroll
    for (int kq=0;kq<16;++kq){
      float4 h4 = *(const float4*)&h[b*68+kq*4];
      float4 w0 = *(const float4*)&Wt[(kq*4+0)*192+gq*4];
      float4 w1 = *(const float4*)&Wt[(kq*4+1)*192+gq*4];
      float4 w2 = *(const float4*)&Wt[(kq*4+2)*192+gq*4];
      float4 w3 = *(const float4*)&Wt[(kq*4+3)*192+gq*4];
      acc.x += h4.x*w0.x + h4.y*w1.x + h4.z*w2.x + h4.w*w3.x;
      acc.y += h4.x*w0.y + h4.y*w1.y + h4.z*w2.y + h4.w*w3.y;
      acc.z += h4.x*w0.z + h4.y*w1.z + h4.z*w2.z + h4.w*w3.z;
      acc.w += h4.x*w0.w + h4.y*w1.w + h4.z*w2.w + h4.w*w3.w;
    }
    *(float4*)&gh[b*196+gq*4] = acc;
    __syncthreads();
    for (int idx=tid; idx<512; idx+=384){
      int bb = idx>>6, j = idx&63;
      const float* xr = xi_t + (sd240 + bb*30 + t)*192 + j;
      float r = sigmoidf_(xr[0]   + gh[bb*196+j]);
      float z = sigmoidf_(xr[64]  + gh[bb*196+64+j]);
      float n = tanhf(   xr[128] + r*gh[bb*196+128+j]);
      float hn = (1.f - z)*n + z*h[bb*68+j];
      h[bb*68+j] = hn;
      full_t[(sd240 + bb*30 + t)*64 + j] = hn;
    }
    __syncthreads();
  }
  // q = W1 h_last + b1
  for (int idx=tid; idx<512; idx+=384){
    int bb = idx>>6, j = idx&63;
    float acc = b1[s*64+j];
    const float* wr = W1 + (size_t)(s*64+j)*64;
    #pragma unroll
    for (int kq=0;kq<16;++kq){
      float4 wv = *(const float4*)(wr+kq*4);
      acc += h[bb*68+kq*4+0]*wv.x + h[bb*68+kq*4+1]*wv.y
           + h[bb*68+kq*4+2]*wv.z + h[bb*68+kq*4+3]*wv.w;
    }
    q[(size_t)bid*512 + idx] = acc;
  }
}

// ---------------------------------------------------------------------------
// Kernel 3: attention projection u = full_t @ W2^T via split-bf16 MFMA, fused
// with score=V.tanh(q+u+b2)+bV, softmax over T, weighted sum -> news.
// One block per (s,d): M=240, N=64, K=64 (2 chunks of 32).
// ---------------------------------------------------------------------------
__global__ __launch_bounds__(256) void k_uproj(
    const float* __restrict__ full_t, const float* __restrict__ q,
    const float* __restrict__ W2, const float* __restrict__ b2,
    const float* __restrict__ V, const float* __restrict__ bV,
    float* __restrict__ news){
  __shared__ short lds[19456];   // Ah[7680] Al[7680] Bh[2048] Bl[2048] = 38912 B
  float* scpart = (float*)&lds[15360];   // aliases B region post-GEMM (1440 floats used)
  float* ssc = scpart + 960;
  float* swt = ssc + 240;
  const int tid = threadIdx.x, lane = tid&63, w = tid>>6, quad = lane>>4;
  const int bid = blockIdx.x;
  const int s = bid/5;
  const size_t sd240 = (size_t)bid*240;

  f32x4 acc[15] = {};
  for (int kc=0; kc<2; ++kc){
    __syncthreads();
    #pragma unroll
    for (int i=0;i<5;++i){
      int idx = tid + i*256;
      if (idx < 1216){
        const float* sp; int dh, ld2;
        if (idx < 960){
          int r = idx>>2, kc8 = idx&3;
          sp = full_t + (sd240 + r)*64 + kc*32 + kc8*8;
          dh = ((r>>4)*64 + ((r&15)|(kc8<<4)))*8; ld2 = 7680;
        } else {
          int c = idx - 960; int j = c>>2, kc8 = c&3;
          sp = W2 + (size_t)(s*64+j)*64 + kc*32 + kc8*8;
          dh = 15360 + ((j>>4)*64 + ((j&15)|(kc8<<4)))*8; ld2 = 2048;
        }
        float4 x0 = *(const float4*)sp;
        float4 x1 = *(const float4*)(sp+4);
        float xs[8] = {x0.x,x0.y,x0.z,x0.w,x1.x,x1.y,x1.z,x1.w};
        U8 hv, lv;
        #pragma unroll
        for (int j2=0;j2<8;++j2) split_bf16(xs[j2], hv.u[j2], lv.u[j2]);
        *(s16x8*)&lds[dh] = hv.v;
        *(s16x8*)&lds[dh+ld2] = lv.v;
      }
    }
    __syncthreads();
    s16x8 bh = *(const s16x8*)&lds[15360 + (w*64+lane)*8];
    s16x8 bl = *(const s16x8*)&lds[17408 + (w*64+lane)*8];
    #pragma unroll
    for (int mt=0;mt<15;++mt){
      s16x8 ah = *(const s16x8*)&lds[(mt*64+lane)*8];
      s16x8 al = *(const s16x8*)&lds[7680+(mt*64+lane)*8];
      acc[mt] = __builtin_amdgcn_mfma_f32_16x16x32_bf16(ah, bh, acc[mt], 0,0,0);
      acc[mt] = __builtin_amdgcn_mfma_f32_16x16x32_bf16(ah, bl, acc[mt], 0,0,0);
      acc[mt] = __builtin_amdgcn_mfma_f32_16x16x32_bf16(al, bh, acc[mt], 0,0,0);
    }
  }
  __syncthreads();   // all waves done reading B region before aliasing it

  // scores: per wave covers 16 j's (n-tile w); reduce tanh(u+q+b2)*V over j
  {
    int j = w*16 + (lane&15);
    float Vj = V[s*64+j], b2j = b2[s*64+j];
    const float* qb = q + (size_t)bid*512;
    #pragma unroll
    for (int mt=0;mt<15;++mt){
      #pragma unroll
      for (int reg=0;reg<4;++reg){
        int row = mt*16 + quad*4 + reg;
        int bb = row/30;
        float val = tanhf(acc[mt][reg] + b2j + qb[bb*64+j]) * Vj;
        val += __shfl_xor(val, 1, 64);
        val += __shfl_xor(val, 2, 64);
        val += __shfl_xor(val, 4, 64);
        val += __shfl_xor(val, 8, 64);
        if ((lane&15)==0) scpart[w*240 + row] = val;
      }
    }
  }
  __syncthreads();
  float bVs = bV[s];
  for (int idx=tid; idx<240; idx+=256)
    ssc[idx] = scpart[idx] + scpart[240+idx] + scpart[480+idx] + scpart[720+idx] + bVs;
  __syncthreads();
  if (tid < 8){
    float mx = -1e30f;
    for (int t=0;t<30;++t) mx = fmaxf(mx, ssc[tid*30+t]);
    float ssum = 0.f;
    for (int t=0;t<30;++t){ float e = expf(ssc[tid*30+t]-mx); swt[tid*30+t] = e; ssum += e; }
    float inv = 1.f/ssum;
    for (int t=0;t<30;++t) swt[tid*30+t] *= inv;
  }
  __syncthreads();
  for (int idx=tid; idx<512; idx+=256){
    int bb = idx>>6, jj = idx&63;
    float a = 0.f;
    for (int t=0;t<30;++t) a += swt[bb*30+t]*full_t[(sd240 + bb*30 + t)*64 + jj];
    news[(size_t)bid*512 + idx] = a;
  }
}

// ---------------------------------------------------------------------------
// Shared helper: 5-step GRU + attention over D=5 (unchanged from R1)
// ---------------------------------------------------------------------------
__device__ void gru5_attn(
    const int s, const int tid,
    float* full, float* h, const float* xi, float* gh, float* scratch,
    const float* __restrict__ Whh, const float* __restrict__ bhh,
    const float* __restrict__ W1, const float* __restrict__ b1,
    const float* __restrict__ W2, const float* __restrict__ b2,
    const float* __restrict__ V, const float* __restrict__ bV,
    float* __restrict__ outvec){
  const int b8 = tid>>5, g0 = tid&31;
  for (int dd=0; dd<5; ++dd){
    for (int r_=0;r_<6;++r_){
      int g = r_*32+g0;
      float acc = bhh[s*192+g];
      const float* wr = Whh + (size_t)(s*192+g)*64;
      #pragma unroll
      for (int kq=0;kq<16;++kq){
        float4 w = *(const float4*)(wr+kq*4);
        acc += h[b8*64+kq*4+0]*w.x + h[b8*64+kq*4+1]*w.y
             + h[b8*64+kq*4+2]*w.z + h[b8*64+kq*4+3]*w.w;
      }
      gh[b8*192+g] = acc;
    }
    __syncthreads();
    for (int idx=tid; idx<512; idx+=256){
      int bb = idx>>6, j = idx&63;
      const float* xr = xi + (bb*5+dd)*192;
      float r = sigmoidf_(xr[j]     + gh[bb*192+j]);
      float z = sigmoidf_(xr[64+j]  + gh[bb*192+64+j]);
      float n = tanhf(   xr[128+j] + r*gh[bb*192+128+j]);
      float hv = h[bb*64+j];
      float hn = (1.f-z)*n + z*hv;
      h[bb*64+j] = hn;
      full[(bb*5+dd)*64 + j] = hn;
    }
    __syncthreads();
  }
  float* qq  = scratch;          // 512
  float* W2t = scratch + 512;    // 4096
  float* Vs  = scratch + 4608;   // 64
  float* b2s = scratch + 4672;   // 64
  float* sc  = scratch + 4736;   // 40
  float* wsm = scratch + 4776;   // 40
  for (int idx=tid; idx<512; idx+=256){
    int bb = idx>>6, j = idx&63;
    float acc = b1[s*64+j];
    const float* wr = W1 + (size_t)(s*64+j)*64;
    #pragma unroll
    for (int kq=0;kq<16;++kq){
      float4 w = *(const float4*)(wr+kq*4);
      acc += h[bb*64+kq*4+0]*w.x + h[bb*64+kq*4+1]*w.y
           + h[bb*64+kq*4+2]*w.z + h[bb*64+kq*4+3]*w.w;
    }
    qq[idx] = acc;
  }
  for (int idx=tid; idx<1024; idx+=256){
    int j = idx>>4, kq = idx&15;
    float4 w = *(const float4*)&W2[(size_t)(s*64+j)*64 + kq*4];
    W2t[(kq*4+0)*64+j]=w.x; W2t[(kq*4+1)*64+j]=w.y;
    W2t[(kq*4+2)*64+j]=w.z; W2t[(kq*4+3)*64+j]=w.w;
  }
  for (int idx=tid; idx<64; idx+=256){ Vs[idx]=V[s*64+idx]; b2s[idx]=b2[s*64+idx]; }
  __syncthreads();
  const int w = tid>>6, lane = tid&63;
  for (int i=0;i<10;++i){
    int pair = w*10+i;
    int bb = pair/5, dd = pair - bb*5;
    float u = qq[bb*64+lane] + b2s[lane];
    #pragma unroll 16
    for (int k=0;k<64;++k) u += W2t[k*64+lane]*full[(bb*5+dd)*64+k];
    float p = warp_sum(tanhf(u)*Vs[lane]);
    if (lane==0) sc[pair] = p + bV[s];
  }
  __syncthreads();
  if (tid<8){
    float mx=-1e30f; for (int dd=0;dd<5;++dd) mx=fmaxf(mx, sc[tid*5+dd]);
    float ssum=0.f;
    for (int dd=0;dd<5;++dd){ float e=expf(sc[tid*5+dd]-mx); wsm[tid*5+dd]=e; ssum+=e; }
    float inv=1.f/ssum;
    for (int dd=0;dd<5;++dd) wsm[tid*5+dd]*=inv;
  }
  __syncthreads();
  for (int idx=tid; idx<512; idx+=256){
    int bb=idx>>6, j=idx&63;
    float acc=0.f;
    for (int dd=0;dd<5;++dd) acc += wsm[bb*5+dd]*full[(bb*5+dd)*64+j];
    outvec[(size_t)(s*8+bb)*64 + j] = acc;
  }
}

// ---------------------------------------------------------------------------
__global__ __launch_bounds__(256) void k_price(
    const float* __restrict__ price,
    const float* __restrict__ Wih, const float* __restrict__ Whh,
    const float* __restrict__ bih, const float* __restrict__ bhh,
    const float* __restrict__ W1, const float* __restrict__ b1,
    const float* __restrict__ W2, const float* __restrict__ b2,
    const float* __restrict__ V, const float* __restrict__ bV,
    float* __restrict__ x_price){
  __shared__ float sm[13000];
  float* full = sm;
  float* h    = sm + 2560;
  float* reg  = sm + 3072;
  float* pr = reg;
  float* xi = reg + 128;
  float* gh = reg + 128 + 7680;
  const int tid = threadIdx.x;
  const int s = blockIdx.x;
  for (int idx=tid; idx<120; idx+=256){
    int bb = idx/15, rem = idx - bb*15; int dd = rem/3, k = rem - dd*3;
    pr[idx] = price[(size_t)((bb*87+s)*5+dd)*3 + k];
  }
  for (int idx=tid; idx<512; idx+=256) h[idx]=0.f;
  __syncthreads();
  for (int idx=tid; idx<7680; idx+=256){
    int bd = idx/192, g = idx - bd*192;
    const float* wr = Wih + (size_t)(s*192+g)*3;
    xi[idx] = bih[s*192+g] + pr[bd*3]*wr[0] + pr[bd*3+1]*wr[1] + pr[bd*3+2]*wr[2];
  }
  __syncthreads();
  gru5_attn(s, tid, full, h, xi, gh, reg, Whh, bhh, W1, b1, W2, b2, V, bV, x_price);
}

__global__ __launch_bounds__(256) void k_day(
    const float* __restrict__ news,
    const float* __restrict__ Wih, const float* __restrict__ Whh,
    const float* __restrict__ bih, const float* __restrict__ bhh,
    const float* __restrict__ W1, const float* __restrict__ b1,
    const float* __restrict__ W2, const float* __restrict__ b2,
    const float* __restrict__ V, const float* __restrict__ bV,
    float* __restrict__ text_vec){
  __shared__ float sm[15000];
  float* full = sm;
  float* h    = sm + 2560;
  float* reg  = sm + 3072;
  float* nw = reg;
  float* xi = reg + 2560;
  float* gh = reg + 2560 + 7680;
  const int tid = threadIdx.x;
  const int s = blockIdx.x;
  for (int idx=tid; idx<2560; idx+=256) nw[idx] = news[(size_t)s*2560 + idx];
  for (int idx=tid; idx<512; idx+=256) h[idx]=0.f;
  __syncthreads();
  for (int idx=tid; idx<7680; idx+=256){
    int bd = idx/192, g = idx - bd*192;
    int bb = bd/5, dd = bd - bb*5;
    const float* wr = Wih + (size_t)(s*192+g)*64;
    const float* xr = nw + (dd*8+bb)*64;
    float acc = bih[s*192+g];
    #pragma unroll
    for (int kq=0;kq<16;++kq){
      float4 w = *(const float4*)(wr+kq*4);
      acc += xr[kq*4+0]*w.x + xr[kq*4+1]*w.y + xr[kq*4+2]*w.z + xr[kq*4+3]*w.w;
    }
    xi[idx]=acc;
  }
  __syncthreads();
  gru5_attn(s, tid, full, h, xi, gh, reg, Whh, bhh, W1, b1, W2, b2, V, bV, text_vec);
}

// ---------------------------------------------------------------------------
// Kernel 5: bilinear fusion; grid (16,87), each wave owns one k (better occupancy)
// ---------------------------------------------------------------------------
__global__ __launch_bounds__(256) void k_bilinear(
    const float* __restrict__ text_vec, const float* __restrict__ x_price,
    const float* __restrict__ bilW, const float* __restrict__ bilb,
    float* __restrict__ ft_vec){
  __shared__ float tv[512], pv[512];
  const int tid = threadIdx.x;
  const int kb = blockIdx.x, s = blockIdx.y;
  for (int idx=tid; idx<512; idx+=256){ tv[idx]=text_vec[s*512+idx]; pv[idx]=x_price[s*512+idx]; }
  __syncthreads();
  const int w = tid>>6, lane = tid&63;
  const int j = (lane&15)*4;
  const int ib = lane>>4;
  float4 pj[8];
  #pragma unroll
  for (int bb=0;bb<8;++bb) pj[bb] = *(const float4*)&pv[bb*64+j];
  const int k = kb*4 + w;
  const float* base = bilW + (size_t)(s*64+k)*4096;
  float acc[8] = {0,0,0,0,0,0,0,0};
  for (int it=0; it<16; ++it){
    float4 wv = *(const float4*)(base + it*256 + lane*4);
    int i = it*4 + ib;
    #pragma unroll
    for (int bb=0;bb<8;++bb){
      float partial = wv.x*pj[bb].x + wv.y*pj[bb].y + wv.z*pj[bb].z + wv.w*pj[bb].w;
      acc[bb] += partial * tv[bb*64+i];
    }
  }
  #pragma unroll
  for (int bb=0;bb<8;++bb){
    float tot = warp_sum(acc[bb]);
    if (lane==0) ft_vec[(size_t)(bb*87+s)*64 + k] = tanhf(tot + bilb[s*64+k]);
  }
}

// ---------------------------------------------------------------------------
__global__ __launch_bounds__(256) void k_gat_wh(
    const float* __restrict__ ft_vec, const float* __restrict__ gatW,
    const float* __restrict__ gata,
    float* __restrict__ Wh_g, float* __restrict__ a1h, float* __restrict__ a2h){
  __shared__ float ftb[5568];
  __shared__ float Ws[4096];
  const int tid = threadIdx.x;
  const int hd = blockIdx.x>>3, b = blockIdx.x&7;
  for (int idx=tid; idx<5568; idx+=256) ftb[idx] = ft_vec[(size_t)b*5568 + idx];
  for (int idx=tid; idx<4096; idx+=256) Ws[idx]  = gatW[(size_t)hd*4096 + idx];
  __syncthreads();
  const int f = tid&63, sq = tid>>6;
  const float af1 = gata[hd*128 + f], af2 = gata[hd*128 + 64 + f];
  for (int p=0;p<22;++p){
    int ss = p*4 + sq;
    if (ss < 87){
      float acc = 0.f;
      #pragma unroll 16
      for (int k=0;k<64;++k) acc += ftb[ss*64+k]*Ws[k*64+f];
      Wh_g[(size_t)((hd*8+b)*87 + ss)*64 + f] = acc;
      float p1 = warp_sum(acc*af1);
      float p2 = warp_sum(acc*af2);
      if (f==0){ a1h[(hd*8+b)*87 + ss] = p1; a2h[(hd*8+b)*87 + ss] = p2; }
    }
  }
}

__global__ __launch_bounds__(256) void k_gat_att(
    const float* __restrict__ Wh_g, const float* __restrict__ a1h,
    const float* __restrict__ a2h, const float* __restrict__ adj,
    float* __restrict__ xg){
  __shared__ float whs[5568];
  __shared__ float a1s[96], a2s[96];
  __shared__ float adjs[7569];
  __shared__ float attw[4*128];
  const int tid = threadIdx.x;
  const int hd = blockIdx.x>>3, b = blockIdx.x&7;
  const int hb = hd*8+b;
  for (int idx=tid; idx<5568; idx+=256) whs[idx] = Wh_g[(size_t)hb*5568 + idx];
  for (int idx=tid; idx<87;   idx+=256){ a1s[idx]=a1h[hb*87+idx]; a2s[idx]=a2h[hb*87+idx]; }
  for (int idx=tid; idx<7569; idx+=256) adjs[idx]=adj[idx];
  __syncthreads();
  const int w = tid>>6, lane = tid&63;
  for (int i=0;i<22;++i){
    int n = w + 4*i;
    if (n < 87){
      float a1n = a1s[n];
      float x1 = a1n + a2s[lane];
      float e1 = (adjs[n*87+lane] > 0.f) ? (x1>0.f? x1 : 0.2f*x1) : -9e15f;
      float e2 = -INFINITY;
      if (lane < 23){
        float x2 = a1n + a2s[64+lane];
        e2 = (adjs[n*87+64+lane] > 0.f) ? (x2>0.f? x2 : 0.2f*x2) : -9e15f;
      }
      float mx  = warp_max(fmaxf(e1,e2));
      float ex1 = expf(e1-mx);
      float ex2 = (lane<23) ? expf(e2-mx) : 0.f;
      float inv = 1.f/warp_sum(ex1+ex2);
      attw[w*128+lane] = ex1*inv;
      if (lane<23) attw[w*128+64+lane] = ex2*inv;
      float o = 0.f;
      for (int m=0;m<87;++m) o += attw[w*128+m]*whs[m*64+lane];
      float val = (o>0.f) ? o : expm1f(o);
      xg[(size_t)(b*87+n)*512 + hd*64 + lane] = val;
    }
  }
}

// ---------------------------------------------------------------------------
// Kernel 8: second GAT layer + out_1 + expected_price; first GEMM wave-parallel
// ---------------------------------------------------------------------------
__global__ __launch_bounds__(256) void k_final(
    const float* __restrict__ xg, const float* __restrict__ ft_vec,
    const float* __restrict__ outW, const float* __restrict__ outa,
    const float* __restrict__ lxW, const float* __restrict__ lxb,
    const float* __restrict__ lpW, const float* __restrict__ lpb,
    const float* __restrict__ adj, float* __restrict__ out){
  __shared__ float whs2[176];
  __shared__ float a1s[96], a2s[96];
  const int tid = threadIdx.x;
  const int b = blockIdx.x;
  const int w = tid>>6, lane = tid&63;
  for (int item=w; item<174; item+=4){
    int ss = item>>1, c = item&1;
    const float* xr = xg + (size_t)(b*87+ss)*512;
    float a = 0.f;
    #pragma unroll
    for (int kk=0;kk<8;++kk) a += xr[kk*64+lane]*outW[(kk*64+lane)*2+c];
    a = warp_sum(a);
    if (lane==0) whs2[item] = a;
  }
  __syncthreads();
  for (int idx=tid; idx<87; idx+=256){
    a1s[idx] = whs2[idx*2]*outa[0] + whs2[idx*2+1]*outa[1];
    a2s[idx] = whs2[idx*2]*outa[2] + whs2[idx*2+1]*outa[3];
  }
  __syncthreads();
  for (int i=0;i<22;++i){
    int n = w + 4*i;
    if (n<87){
      float a1n = a1s[n];
      float x1 = a1n + a2s[lane];
      float e1 = (adj[n*87+lane]>0.f) ? (x1>0.f?x1:0.2f*x1) : -9e15f;
      float e2 = -INFINITY;
      if (lane<23){
        float x2 = a1n + a2s[64+lane];
        e2 = (adj[n*87+64+lane]>0.f) ? (x2>0.f?x2:0.2f*x2) : -9e15f;
      }
      float mx  = warp_max(fmaxf(e1,e2));
      float ex1 = expf(e1-mx);
      float ex2 = (lane<23)?expf(e2-mx):0.f;
      float inv = 1.f/warp_sum(ex1+ex2);
      float at1 = ex1*inv, at2 = ex2*inv;
      float p0 = at1*whs2[lane*2];
      float p1 = at1*whs2[lane*2+1];
      if (lane<23){ p0 += at2*whs2[(64+lane)*2]; p1 += at2*whs2[(64+lane)*2+1]; }
      float s0 = warp_sum(p0);
      float s1 = warp_sum(p1);
      float ftv = ft_vec[(size_t)(b*87+n)*64 + lane];
      float d0 = warp_sum(ftv*lxW[lane]);
      float d1 = warp_sum(ftv*lxW[64+lane]);
      float dp = warp_sum(ftv*lpW[lane]);
      if (lane==0){
        float ep  = tanhf(dp + lpb[0])*0.01f;
        float o10 = tanhf(d0 + lxb[0]);
        float o11 = tanhf(d1 + lxb[1]);
        float g0 = (s0>0.f)?s0:expm1f(s0);
        float g1 = (s1>0.f)?s1:expm1f(s1);
        float* op = out + (size_t)(b*87+n)*3;
        op[0] = ep; op[1] = g0 + o10; op[2] = g1 + o11;
      }
    }
  }
}

// ---------------------------------------------------------------------------
extern "C" void kernel_launch(void* const* d_in, const int* in_sizes, int n_in,
                              void* d_out, int out_size, void* d_ws, size_t ws_size,
                              hipStream_t stream){
  const float* text      = (const float*)d_in[0];
  const float* price     = (const float*)d_in[1];
  const float* adj       = (const float*)d_in[2];
  const float* grup_Wih  = (const float*)d_in[4];
  const float* grup_Whh  = (const float*)d_in[5];
  const float* grup_bih  = (const float*)d_in[6];
  const float* grup_bhh  = (const float*)d_in[7];
  const float* tgru_Wih  = (const float*)d_in[8];
  const float* tgru_Whh  = (const float*)d_in[9];
  const float* tgru_bih  = (const float*)d_in[10];
  const float* tgru_bhh  = (const float*)d_in[11];
  const float* grut_Wih  = (const float*)d_in[12];
  const float* grut_Whh  = (const float*)d_in[13];
  const float* grut_bih  = (const float*)d_in[14];
  const float* grut_bhh  = (const float*)d_in[15];
  const float* attnp_W1  = (const float*)d_in[16];
  const float* attnp_b1  = (const float*)d_in[17];
  const float* attnp_W2  = (const float*)d_in[18];
  const float* attnp_b2  = (const float*)d_in[19];
  const float* attnp_V   = (const float*)d_in[20];
  const float* attnp_bV  = (const float*)d_in[21];
  const float* attw_W1   = (const float*)d_in[22];
  const float* attw_b1   = (const float*)d_in[23];
  const float* attw_W2   = (const float*)d_in[24];
  const float* attw_b2   = (const float*)d_in[25];
  const float* attw_V    = (const float*)d_in[26];
  const float* attw_bV   = (const float*)d_in[27];
  const float* attnt_W1  = (const float*)d_in[28];
  const float* attnt_b1  = (const float*)d_in[29];
  const float* attnt_W2  = (const float*)d_in[30];
  const float* attnt_b2  = (const float*)d_in[31];
  const float* attnt_V   = (const float*)d_in[32];
  const float* attnt_bV  = (const float*)d_in[33];
  const float* bil_W     = (const float*)d_in[34];
  const float* bil_b     = (const float*)d_in[35];
  const float* lx_W      = (const float*)d_in[36];
  const float* lx_b      = (const float*)d_in[37];
  const float* lp_W      = (const float*)d_in[38];
  const float* lp_b      = (const float*)d_in[39];
  const float* gat_W     = (const float*)d_in[40];
  const float* gat_a     = (const float*)d_in[41];
  const float* out_W     = (const float*)d_in[42];
  const float* out_a     = (const float*)d_in[43];

  // workspace layout (floats); total 121.2 MB (unchanged from R1)
  float* ws       = (float*)d_ws;
  float* xi_t     = ws;                      // 20,044,800
  float* full_t   = xi_t   + 20044800;       //  6,681,600
  float* news     = full_t + 6681600;        //    222,720
  float* x_price  = news   + 222720;         //     44,544
  float* text_vec = x_price + 44544;         //     44,544
  float* ft_vec   = text_vec + 44544;        //     44,544
  float* Wh_g     = ft_vec + 44544;          //  2,850,816
  float* a1h      = Wh_g   + 2850816;        //      5,568
  float* a2h      = a1h    + 5568;           //      5,568
  float* xg       = a2h    + 5568;           //    356,352
  // q aliases Wh_g: q written k_gru30, read k_uproj; Wh_g written k_gat_wh (later)
  float* q        = Wh_g;

  k_tweet_proj<<<dim3(3,5,87),256,0,stream>>>(text, tgru_Wih, tgru_bih, xi_t);
  k_gru30<<<435,384,0,stream>>>(xi_t, tgru_Whh, tgru_bhh, attw_W1, attw_b1, full_t, q);
  k_uproj<<<435,256,0,stream>>>(full_t, q, attw_W2, attw_b2, attw_V, attw_bV, news);
  k_price<<<87,256,0,stream>>>(price, grup_Wih, grup_Whh, grup_bih, grup_bhh,
      attnp_W1, attnp_b1, attnp_W2, attnp_b2, attnp_V, attnp_bV, x_price);
  k_day<<<87,256,0,stream>>>(news, grut_Wih, grut_Whh, grut_bih, grut_bhh,
      attnt_W1, attnt_b1, attnt_W2, attnt_b2, attnt_V, attnt_bV, text_vec);
  k_bilinear<<<dim3(16,87),256,0,stream>>>(text_vec, x_price, bil_W, bil_b, ft_vec);
  k_gat_wh<<<64,256,0,stream>>>(ft_vec, gat_W, gat_a, Wh_g, a1h, a2h);
  k_gat_att<<<64,256,0,stream>>>(Wh_g, a1h, a2h, adj, xg);
  k_final<<<8,256,0,stream>>>(xg, ft_vec, out_W, out_a, lx_W, lx_b, lp_W, lp_b,
      adj, (float*)d_out);
}

// Round 3
// 1035.575 us; speedup vs baseline: 1.3937x; 1.0947x over previous
//
#include <hip/hip_runtime.h>
#include <math.h>

// Model dims: S=87, B=8, D=5, T=30, H=64, G=192, K_text=512

typedef short s16x8 __attribute__((ext_vector_type(8)));
typedef float f32x4 __attribute__((ext_vector_type(4)));

__device__ __forceinline__ float sigmoidf_(float x){ return 1.0f/(1.0f+expf(-x)); }

__device__ __forceinline__ float warp_sum(float v){
  #pragma unroll
  for (int off=32; off>0; off>>=1) v += __shfl_xor(v, off, 64);
  return v;
}
__device__ __forceinline__ float warp_max(float v){
  #pragma unroll
  for (int off=32; off>0; off>>=1) v = fmaxf(v, __shfl_xor(v, off, 64));
  return v;
}

// truncation split: x ~= hi + lo with |err| ~ 2^-14 |x| (3 VALU ops/elem)
__device__ __forceinline__ void split_bf16(float x, unsigned short& hi, unsigned short& lo){
  unsigned u = __float_as_uint(x);
  hi = (unsigned short)(u >> 16);
  float r = x - __uint_as_float(u & 0xffff0000u);
  lo = (unsigned short)(__float_as_uint(r) >> 16);
}

union U8 { unsigned short u[8]; s16x8 v; };

// ---------------------------------------------------------------------------
// Kernel 1: tweet input projection via split-bf16 MFMA.
// xi_t[s,d,row,g] = sum_k text[b,s,d,t,k]*Wih[s,g,k] + bih[s,g], row=b*30+t
// Per block: M=80, N=192, K=512 in 16 chunks of 32.
// Staging is slot-major: thread handles LDS fragment slots directly ->
// ds_write_b128 conflict-free, loads batched (10 in flight) before convert.
// ---------------------------------------------------------------------------
__global__ __launch_bounds__(256) void k_tweet_proj(
    const float* __restrict__ text, const float* __restrict__ Wih,
    const float* __restrict__ bih, float* __restrict__ xi_t){
  __shared__ short lds[17408];   // Ah[2560] Al[2560] Bh[6144] Bl[6144] shorts = 34816 B
  const int tid = threadIdx.x;
  const int mb = blockIdx.x, d = blockIdx.y, s = blockIdx.z;
  const int lane = tid & 63, w = tid >> 6, quad = lane >> 4;

  // chunk table: 1088 chunks = 17 tiles x 64 slots; tile 0..4 = A, 5..16 = B.
  // chunk c: slot=c&63, k8=slot>>4, i16=slot&15. LDS dst = contiguous 16B per slot.
  const float* srcp[5]; int dsth[5]; int dstl[5]; bool val[5];
  #pragma unroll
  for (int i=0;i<5;++i){
    int c = tid + i*256;
    val[i] = (c < 1088);
    int cc = val[i] ? c : 0;
    int tile = cc>>6, slot = cc&63, k8 = slot>>4, i16 = slot&15;
    if (tile < 5){
      int row = mb*80 + tile*16 + i16;           // always < 240
      int b = row/30, t = row - b*30;
      srcp[i] = text + (size_t)(b*13050 + s*150 + d*30 + t)*512 + k8*8;
      dsth[i] = tile*512 + slot*8;
      dstl[i] = dsth[i] + 2560;
    } else {
      int g = (tile-5)*16 + i16;
      srcp[i] = Wih + (size_t)(s*192+g)*512 + k8*8;
      dsth[i] = 5120 + (tile-5)*512 + slot*8;
      dstl[i] = dsth[i] + 6144;
    }
  }

  f32x4 acc[5][3] = {};

  for (int kc=0; kc<16; ++kc){
    __syncthreads();
    float4 v0[5], v1[5];
    #pragma unroll
    for (int i=0;i<5;++i){
      if (val[i]){
        const float* sp = srcp[i] + kc*32;
        v0[i] = *(const float4*)sp;
        v1[i] = *(const float4*)(sp+4);
      }
    }
    #pragma unroll
    for (int i=0;i<5;++i){
      if (val[i]){
        float xs[8] = {v0[i].x,v0[i].y,v0[i].z,v0[i].w,v1[i].x,v1[i].y,v1[i].z,v1[i].w};
        U8 hv, lv;
        #pragma unroll
        for (int j=0;j<8;++j) split_bf16(xs[j], hv.u[j], lv.u[j]);
        *(s16x8*)&lds[dsth[i]] = hv.v;
        *(s16x8*)&lds[dstl[i]] = lv.v;
      }
    }
    __syncthreads();
    s16x8 ah[5], al[5], bh[3], bl[3];
    #pragma unroll
    for (int mt=0;mt<5;++mt){
      ah[mt] = *(const s16x8*)&lds[mt*512 + lane*8];
      al[mt] = *(const s16x8*)&lds[2560 + mt*512 + lane*8];
    }
    #pragma unroll
    for (int nl=0;nl<3;++nl){
      int nt = w*3+nl;
      bh[nl] = *(const s16x8*)&lds[5120 + nt*512 + lane*8];
      bl[nl] = *(const s16x8*)&lds[11264 + nt*512 + lane*8];
    }
    #pragma unroll
    for (int mt=0;mt<5;++mt){
      #pragma unroll
      for (int nl=0;nl<3;++nl){
        acc[mt][nl] = __builtin_amdgcn_mfma_f32_16x16x32_bf16(ah[mt], bh[nl], acc[mt][nl], 0,0,0);
        acc[mt][nl] = __builtin_amdgcn_mfma_f32_16x16x32_bf16(ah[mt], bl[nl], acc[mt][nl], 0,0,0);
        acc[mt][nl] = __builtin_amdgcn_mfma_f32_16x16x32_bf16(al[mt], bh[nl], acc[mt][nl], 0,0,0);
      }
    }
  }

  // epilogue: C/D layout col=lane&15, row=quad*4+reg
  const size_t obase = (size_t)(s*5+d)*240;
  #pragma unroll
  for (int nl=0;nl<3;++nl){
    int g = (w*3+nl)*16 + (lane&15);
    float bias = bih[s*192+g];
    #pragma unroll
    for (int mt=0;mt<5;++mt){
      #pragma unroll
      for (int reg=0;reg<4;++reg){
        int row = mb*80 + mt*16 + quad*4 + reg;
        xi_t[(obase+row)*192 + g] = acc[mt][nl][reg] + bias;
      }
    }
  }
}

// ---------------------------------------------------------------------------
// Kernel 2: tweet GRU (30 steps), one block per (s,d).
// xi rows for step t+1 prefetched into registers during step t's gate phase.
// ---------------------------------------------------------------------------
__global__ __launch_bounds__(384) void k_gru30(
    const float* __restrict__ xi_t, const float* __restrict__ Whh, const float* __restrict__ bhh,
    const float* __restrict__ W1, const float* __restrict__ b1,
    float* __restrict__ full_t, float* __restrict__ q){
  __shared__ float sm[14400];
  float* Wt = sm;          // 12288: Wt[k*192+g] = Whh[s,g,k]
  float* h  = sm + 12288;  // 8*68
  float* gh = sm + 12832;  // 8*196
  const int tid = threadIdx.x;
  const int bid = blockIdx.x;
  const int s = bid/5;
  for (int idx = tid; idx < 3072; idx += 384){
    int g = idx >> 4, kq = idx & 15;
    float4 wv = *(const float4*)&Whh[(size_t)(s*192+g)*64 + kq*4];
    Wt[(kq*4+0)*192 + g] = wv.x;
    Wt[(kq*4+1)*192 + g] = wv.y;
    Wt[(kq*4+2)*192 + g] = wv.z;
    Wt[(kq*4+3)*192 + g] = wv.w;
  }
  for (int idx = tid; idx < 544; idx += 384) h[idx] = 0.f;
  const int gq = tid>>3, b = tid&7;        // gq 0..47, b 0..7
  float4 bh4 = *(const float4*)&bhh[s*192 + gq*4];

  const size_t sd240 = (size_t)bid*240;
  // xi prefetch registers: thread owns idx=tid (if<512) and idx=tid+384 (tid<128)
  float xp[2][3];
  #pragma unroll
  for (int u2=0;u2<2;++u2){
    int idx = tid + u2*384;
    if (idx < 512){
      int bb = idx>>6, j = idx&63;
      const float* xr = xi_t + (sd240 + bb*30 + 0)*192 + j;
      xp[u2][0]=xr[0]; xp[u2][1]=xr[64]; xp[u2][2]=xr[128];
    }
  }
  __syncthreads();

  for (int t=0; t<30; ++t){
    float4 acc = bh4;
    #pragma unroll
    for (int kq=0;kq<16;++kq){
      float4 h4 = *(const float4*)&h[b*68+kq*4];
      float4 w0 = *(const float4*)&Wt[(kq*4+0)*192+gq*4];
      float4 w1 = *(const float4*)&Wt[(kq*4+1)*192+gq*4];
      float4 w2 = *(const float4*)&Wt[(kq*4+2)*192+gq*4];
      float4 w3 = *(const float4*)&Wt[(kq*4+3)*192+gq*4];
      acc.x += h4.x*w0.x + h4.y*w1.x + h4.z*w2.x + h4.w*w3.x;
      acc.y += h4.x*w0.y + h4.y*w1.y + h4.z*w2.y + h4.w*w3.y;
      acc.z += h4.x*w0.z + h4.y*w1.z + h4.z*w2.z + h4.w*w3.z;
      acc.w += h4.x*w0.w + h4.y*w1.w + h4.z*w2.w + h4.w*w3.w;
    }
    *(float4*)&gh[b*196+gq*4] = acc;
    __syncthreads();
    float cur[2][3];
    #pragma unroll
    for (int u2=0;u2<2;++u2){ cur[u2][0]=xp[u2][0]; cur[u2][1]=xp[u2][1]; cur[u2][2]=xp[u2][2]; }
    if (t < 29){
      #pragma unroll
      for (int u2=0;u2<2;++u2){
        int idx = tid + u2*384;
        if (idx < 512){
          int bb = idx>>6, j = idx&63;
          const float* xr = xi_t + (sd240 + bb*30 + t + 1)*192 + j;
          xp[u2][0]=xr[0]; xp[u2][1]=xr[64]; xp[u2][2]=xr[128];
        }
      }
    }
    #pragma unroll
    for (int u2=0;u2<2;++u2){
      int idx = tid + u2*384;
      if (idx < 512){
        int bb = idx>>6, j = idx&63;
        float r = sigmoidf_(cur[u2][0] + gh[bb*196+j]);
        float z = sigmoidf_(cur[u2][1] + gh[bb*196+64+j]);
        float n = tanhf(   cur[u2][2] + r*gh[bb*196+128+j]);
        float hn = (1.f - z)*n + z*h[bb*68+j];
        h[bb*68+j] = hn;
        full_t[(sd240 + bb*30 + t)*64 + j] = hn;
      }
    }
    __syncthreads();
  }
  // q = W1 h_last + b1
  for (int idx=tid; idx<512; idx+=384){
    int bb = idx>>6, j = idx&63;
    float acc = b1[s*64+j];
    const float* wr = W1 + (size_t)(s*64+j)*64;
    #pragma unroll
    for (int kq=0;kq<16;++kq){
      float4 wv = *(const float4*)(wr+kq*4);
      acc += h[bb*68+kq*4+0]*wv.x + h[bb*68+kq*4+1]*wv.y
           + h[bb*68+kq*4+2]*wv.z + h[bb*68+kq*4+3]*wv.w;
    }
    q[(size_t)bid*512 + idx] = acc;
  }
}

// ---------------------------------------------------------------------------
// Kernel 3: attention projection u = full_t @ W2^T via split-bf16 MFMA, fused
// with score=V.tanh(q+u+b2)+bV, softmax over T, weighted sum -> news.
// ---------------------------------------------------------------------------
__global__ __launch_bounds__(256) void k_uproj(
    const float* __restrict__ full_t, const float* __restrict__ q,
    const float* __restrict__ W2, const float* __restrict__ b2,
    const float* __restrict__ V, const float* __restrict__ bV,
    float* __restrict__ news){
  __shared__ short lds[19456];   // Ah[7680] Al[7680] Bh[2048] Bl[2048] = 38912 B
  float* scpart = (float*)&lds[15360];
  float* ssc = scpart + 960;
  float* swt = ssc + 240;
  const int tid = threadIdx.x, lane = tid&63, w = tid>>6, quad = lane>>4;
  const int bid = blockIdx.x;
  const int s = bid/5;
  const size_t sd240 = (size_t)bid*240;

  f32x4 acc[15] = {};
  for (int kc=0; kc<2; ++kc){
    __syncthreads();
    #pragma unroll
    for (int i=0;i<5;++i){
      int idx = tid + i*256;
      if (idx < 1216){
        const float* sp; int dh, ld2;
        if (idx < 960){
          int r = idx>>2, kc8 = idx&3;
          sp = full_t + (sd240 + r)*64 + kc*32 + kc8*8;
          dh = ((r>>4)*64 + ((r&15)|(kc8<<4)))*8; ld2 = 7680;
        } else {
          int c = idx - 960; int j = c>>2, kc8 = c&3;
          sp = W2 + (size_t)(s*64+j)*64 + kc*32 + kc8*8;
          dh = 15360 + ((j>>4)*64 + ((j&15)|(kc8<<4)))*8; ld2 = 2048;
        }
        float4 x0 = *(const float4*)sp;
        float4 x1 = *(const float4*)(sp+4);
        float xs[8] = {x0.x,x0.y,x0.z,x0.w,x1.x,x1.y,x1.z,x1.w};
        U8 hv, lv;
        #pragma unroll
        for (int j2=0;j2<8;++j2) split_bf16(xs[j2], hv.u[j2], lv.u[j2]);
        *(s16x8*)&lds[dh] = hv.v;
        *(s16x8*)&lds[dh+ld2] = lv.v;
      }
    }
    __syncthreads();
    s16x8 bh = *(const s16x8*)&lds[15360 + (w*64+lane)*8];
    s16x8 bl = *(const s16x8*)&lds[17408 + (w*64+lane)*8];
    #pragma unroll
    for (int mt=0;mt<15;++mt){
      s16x8 ah = *(const s16x8*)&lds[(mt*64+lane)*8];
      s16x8 al = *(const s16x8*)&lds[7680+(mt*64+lane)*8];
      acc[mt] = __builtin_amdgcn_mfma_f32_16x16x32_bf16(ah, bh, acc[mt], 0,0,0);
      acc[mt] = __builtin_amdgcn_mfma_f32_16x16x32_bf16(ah, bl, acc[mt], 0,0,0);
      acc[mt] = __builtin_amdgcn_mfma_f32_16x16x32_bf16(al, bh, acc[mt], 0,0,0);
    }
  }
  __syncthreads();

  {
    int j = w*16 + (lane&15);
    float Vj = V[s*64+j], b2j = b2[s*64+j];
    const float* qb = q + (size_t)bid*512;
    #pragma unroll
    for (int mt=0;mt<15;++mt){
      #pragma unroll
      for (int reg=0;reg<4;++reg){
        int row = mt*16 + quad*4 + reg;
        int bb = row/30;
        float val = tanhf(acc[mt][reg] + b2j + qb[bb*64+j]) * Vj;
        val += __shfl_xor(val, 1, 64);
        val += __shfl_xor(val, 2, 64);
        val += __shfl_xor(val, 4, 64);
        val += __shfl_xor(val, 8, 64);
        if ((lane&15)==0) scpart[w*240 + row] = val;
      }
    }
  }
  __syncthreads();
  float bVs = bV[s];
  for (int idx=tid; idx<240; idx+=256)
    ssc[idx] = scpart[idx] + scpart[240+idx] + scpart[480+idx] + scpart[720+idx] + bVs;
  __syncthreads();
  if (tid < 8){
    float mx = -1e30f;
    for (int t=0;t<30;++t) mx = fmaxf(mx, ssc[tid*30+t]);
    float ssum = 0.f;
    for (int t=0;t<30;++t){ float e = expf(ssc[tid*30+t]-mx); swt[tid*30+t] = e; ssum += e; }
    float inv = 1.f/ssum;
    for (int t=0;t<30;++t) swt[tid*30+t] *= inv;
  }
  __syncthreads();
  for (int idx=tid; idx<512; idx+=256){
    int bb = idx>>6, jj = idx&63;
    float a = 0.f;
    for (int t=0;t<30;++t) a += swt[bb*30+t]*full_t[(sd240 + bb*30 + t)*64 + jj];
    news[(size_t)bid*512 + idx] = a;
  }
}

// ---------------------------------------------------------------------------
// Shared helper: 5-step GRU + attention over D=5
// ---------------------------------------------------------------------------
__device__ void gru5_attn(
    const int s, const int tid,
    float* full, float* h, const float* xi, float* gh, float* scratch,
    const float* __restrict__ Whh, const float* __restrict__ bhh,
    const float* __restrict__ W1, const float* __restrict__ b1,
    const float* __restrict__ W2, const float* __restrict__ b2,
    const float* __restrict__ V, const float* __restrict__ bV,
    float* __restrict__ outvec){
  const int b8 = tid>>5, g0 = tid&31;
  for (int dd=0; dd<5; ++dd){
    for (int r_=0;r_<6;++r_){
      int g = r_*32+g0;
      float acc = bhh[s*192+g];
      const float* wr = Whh + (size_t)(s*192+g)*64;
      #pragma unroll
      for (int kq=0;kq<16;++kq){
        float4 w = *(const float4*)(wr+kq*4);
        acc += h[b8*64+kq*4+0]*w.x + h[b8*64+kq*4+1]*w.y
             + h[b8*64+kq*4+2]*w.z + h[b8*64+kq*4+3]*w.w;
      }
      gh[b8*192+g] = acc;
    }
    __syncthreads();
    for (int idx=tid; idx<512; idx+=256){
      int bb = idx>>6, j = idx&63;
      const float* xr = xi + (bb*5+dd)*192;
      float r = sigmoidf_(xr[j]     + gh[bb*192+j]);
      float z = sigmoidf_(xr[64+j]  + gh[bb*192+64+j]);
      float n = tanhf(   xr[128+j] + r*gh[bb*192+128+j]);
      float hv = h[bb*64+j];
      float hn = (1.f-z)*n + z*hv;
      h[bb*64+j] = hn;
      full[(bb*5+dd)*64 + j] = hn;
    }
    __syncthreads();
  }
  float* qq  = scratch;
  float* W2t = scratch + 512;
  float* Vs  = scratch + 4608;
  float* b2s = scratch + 4672;
  float* sc  = scratch + 4736;
  float* wsm = scratch + 4776;
  for (int idx=tid; idx<512; idx+=256){
    int bb = idx>>6, j = idx&63;
    float acc = b1[s*64+j];
    const float* wr = W1 + (size_t)(s*64+j)*64;
    #pragma unroll
    for (int kq=0;kq<16;++kq){
      float4 w = *(const float4*)(wr+kq*4);
      acc += h[bb*64+kq*4+0]*w.x + h[bb*64+kq*4+1]*w.y
           + h[bb*64+kq*4+2]*w.z + h[bb*64+kq*4+3]*w.w;
    }
    qq[idx] = acc;
  }
  for (int idx=tid; idx<1024; idx+=256){
    int j = idx>>4, kq = idx&15;
    float4 w = *(const float4*)&W2[(size_t)(s*64+j)*64 + kq*4];
    W2t[(kq*4+0)*64+j]=w.x; W2t[(kq*4+1)*64+j]=w.y;
    W2t[(kq*4+2)*64+j]=w.z; W2t[(kq*4+3)*64+j]=w.w;
  }
  for (int idx=tid; idx<64; idx+=256){ Vs[idx]=V[s*64+idx]; b2s[idx]=b2[s*64+idx]; }
  __syncthreads();
  const int w = tid>>6, lane = tid&63;
  for (int i=0;i<10;++i){
    int pair = w*10+i;
    int bb = pair/5, dd = pair - bb*5;
    float u = qq[bb*64+lane] + b2s[lane];
    #pragma unroll 16
    for (int k=0;k<64;++k) u += W2t[k*64+lane]*full[(bb*5+dd)*64+k];
    float p = warp_sum(tanhf(u)*Vs[lane]);
    if (lane==0) sc[pair] = p + bV[s];
  }
  __syncthreads();
  if (tid<8){
    float mx=-1e30f; for (int dd=0;dd<5;++dd) mx=fmaxf(mx, sc[tid*5+dd]);
    float ssum=0.f;
    for (int dd=0;dd<5;++dd){ float e=expf(sc[tid*5+dd]-mx); wsm[tid*5+dd]=e; ssum+=e; }
    float inv=1.f/ssum;
    for (int dd=0;dd<5;++dd) wsm[tid*5+dd]*=inv;
  }
  __syncthreads();
  for (int idx=tid; idx<512; idx+=256){
    int bb=idx>>6, j=idx&63;
    float acc=0.f;
    for (int dd=0;dd<5;++dd) acc += wsm[bb*5+dd]*full[(bb*5+dd)*64+j];
    outvec[(size_t)(s*8+bb)*64 + j] = acc;
  }
}

// ---------------------------------------------------------------------------
__global__ __launch_bounds__(256) void k_price(
    const float* __restrict__ price,
    const float* __restrict__ Wih, const float* __restrict__ Whh,
    const float* __restrict__ bih, const float* __restrict__ bhh,
    const float* __restrict__ W1, const float* __restrict__ b1,
    const float* __restrict__ W2, const float* __restrict__ b2,
    const float* __restrict__ V, const float* __restrict__ bV,
    float* __restrict__ x_price){
  __shared__ float sm[13000];
  float* full = sm;
  float* h    = sm + 2560;
  float* reg  = sm + 3072;
  float* pr = reg;
  float* xi = reg + 128;
  float* gh = reg + 128 + 7680;
  const int tid = threadIdx.x;
  const int s = blockIdx.x;
  for (int idx=tid; idx<120; idx+=256){
    int bb = idx/15, rem = idx - bb*15; int dd = rem/3, k = rem - dd*3;
    pr[idx] = price[(size_t)((bb*87+s)*5+dd)*3 + k];
  }
  for (int idx=tid; idx<512; idx+=256) h[idx]=0.f;
  __syncthreads();
  for (int idx=tid; idx<7680; idx+=256){
    int bd = idx/192, g = idx - bd*192;
    const float* wr = Wih + (size_t)(s*192+g)*3;
    xi[idx] = bih[s*192+g] + pr[bd*3]*wr[0] + pr[bd*3+1]*wr[1] + pr[bd*3+2]*wr[2];
  }
  __syncthreads();
  gru5_attn(s, tid, full, h, xi, gh, reg, Whh, bhh, W1, b1, W2, b2, V, bV, x_price);
}

__global__ __launch_bounds__(256) void k_day(
    const float* __restrict__ news,
    const float* __restrict__ Wih, const float* __restrict__ Whh,
    const float* __restrict__ bih, const float* __restrict__ bhh,
    const float* __restrict__ W1, const float* __restrict__ b1,
    const float* __restrict__ W2, const float* __restrict__ b2,
    const float* __restrict__ V, const float* __restrict__ bV,
    float* __restrict__ text_vec){
  __shared__ float sm[15000];
  float* full = sm;
  float* h    = sm + 2560;
  float* reg  = sm + 3072;
  float* nw = reg;
  float* xi = reg + 2560;
  float* gh = reg + 2560 + 7680;
  const int tid = threadIdx.x;
  const int s = blockIdx.x;
  for (int idx=tid; idx<2560; idx+=256) nw[idx] = news[(size_t)s*2560 + idx];
  for (int idx=tid; idx<512; idx+=256) h[idx]=0.f;
  __syncthreads();
  for (int idx=tid; idx<7680; idx+=256){
    int bd = idx/192, g = idx - bd*192;
    int bb = bd/5, dd = bd - bb*5;
    const float* wr = Wih + (size_t)(s*192+g)*64;
    const float* xr = nw + (dd*8+bb)*64;
    float acc = bih[s*192+g];
    #pragma unroll
    for (int kq=0;kq<16;++kq){
      float4 w = *(const float4*)(wr+kq*4);
      acc += xr[kq*4+0]*w.x + xr[kq*4+1]*w.y + xr[kq*4+2]*w.z + xr[kq*4+3]*w.w;
    }
    xi[idx]=acc;
  }
  __syncthreads();
  gru5_attn(s, tid, full, h, xi, gh, reg, Whh, bhh, W1, b1, W2, b2, V, bV, text_vec);
}

// ---------------------------------------------------------------------------
__global__ __launch_bounds__(256) void k_bilinear(
    const float* __restrict__ text_vec, const float* __restrict__ x_price,
    const float* __restrict__ bilW, const float* __restrict__ bilb,
    float* __restrict__ ft_vec){
  __shared__ float tv[512], pv[512];
  const int tid = threadIdx.x;
  const int kb = blockIdx.x, s = blockIdx.y;
  for (int idx=tid; idx<512; idx+=256){ tv[idx]=text_vec[s*512+idx]; pv[idx]=x_price[s*512+idx]; }
  __syncthreads();
  const int w = tid>>6, lane = tid&63;
  const int j = (lane&15)*4;
  const int ib = lane>>4;
  float4 pj[8];
  #pragma unroll
  for (int bb=0;bb<8;++bb) pj[bb] = *(const float4*)&pv[bb*64+j];
  const int k = kb*4 + w;
  const float* base = bilW + (size_t)(s*64+k)*4096;
  float acc[8] = {0,0,0,0,0,0,0,0};
  for (int it=0; it<16; ++it){
    float4 wv = *(const float4*)(base + it*256 + lane*4);
    int i = it*4 + ib;
    #pragma unroll
    for (int bb=0;bb<8;++bb){
      float partial = wv.x*pj[bb].x + wv.y*pj[bb].y + wv.z*pj[bb].z + wv.w*pj[bb].w;
      acc[bb] += partial * tv[bb*64+i];
    }
  }
  #pragma unroll
  for (int bb=0;bb<8;++bb){
    float tot = warp_sum(acc[bb]);
    if (lane==0) ft_vec[(size_t)(bb*87+s)*64 + k] = tanhf(tot + bilb[s*64+k]);
  }
}

// ---------------------------------------------------------------------------
__global__ __launch_bounds__(256) void k_gat_wh(
    const float* __restrict__ ft_vec, const float* __restrict__ gatW,
    const float* __restrict__ gata,
    float* __restrict__ Wh_g, float* __restrict__ a1h, float* __restrict__ a2h){
  __shared__ float ftb[5568];
  __shared__ float Ws[4096];
  const int tid = threadIdx.x;
  const int hd = blockIdx.x>>3, b = blockIdx.x&7;
  for (int idx=tid; idx<5568; idx+=256) ftb[idx] = ft_vec[(size_t)b*5568 + idx];
  for (int idx=tid; idx<4096; idx+=256) Ws[idx]  = gatW[(size_t)hd*4096 + idx];
  __syncthreads();
  const int f = tid&63, sq = tid>>6;
  const float af1 = gata[hd*128 + f], af2 = gata[hd*128 + 64 + f];
  for (int p=0;p<22;++p){
    int ss = p*4 + sq;
    if (ss < 87){
      float acc = 0.f;
      #pragma unroll 16
      for (int k=0;k<64;++k) acc += ftb[ss*64+k]*Ws[k*64+f];
      Wh_g[(size_t)((hd*8+b)*87 + ss)*64 + f] = acc;
      float p1 = warp_sum(acc*af1);
      float p2 = warp_sum(acc*af2);
      if (f==0){ a1h[(hd*8+b)*87 + ss] = p1; a2h[(hd*8+b)*87 + ss] = p2; }
    }
  }
}

__global__ __launch_bounds__(256) void k_gat_att(
    const float* __restrict__ Wh_g, const float* __restrict__ a1h,
    const float* __restrict__ a2h, const float* __restrict__ adj,
    float* __restrict__ xg){
  __shared__ float whs[5568];
  __shared__ float a1s[96], a2s[96];
  __shared__ float adjs[7569];
  __shared__ float attw[4*128];
  const int tid = threadIdx.x;
  const int hd = blockIdx.x>>3, b = blockIdx.x&7;
  const int hb = hd*8+b;
  for (int idx=tid; idx<5568; idx+=256) whs[idx] = Wh_g[(size_t)hb*5568 + idx];
  for (int idx=tid; idx<87;   idx+=256){ a1s[idx]=a1h[hb*87+idx]; a2s[idx]=a2h[hb*87+idx]; }
  for (int idx=tid; idx<7569; idx+=256) adjs[idx]=adj[idx];
  __syncthreads();
  const int w = tid>>6, lane = tid&63;
  for (int i=0;i<22;++i){
    int n = w + 4*i;
    if (n < 87){
      float a1n = a1s[n];
      float x1 = a1n + a2s[lane];
      float e1 = (adjs[n*87+lane] > 0.f) ? (x1>0.f? x1 : 0.2f*x1) : -9e15f;
      float e2 = -INFINITY;
      if (lane < 23){
        float x2 = a1n + a2s[64+lane];
        e2 = (adjs[n*87+64+lane] > 0.f) ? (x2>0.f? x2 : 0.2f*x2) : -9e15f;
      }
      float mx  = warp_max(fmaxf(e1,e2));
      float ex1 = expf(e1-mx);
      float ex2 = (lane<23) ? expf(e2-mx) : 0.f;
      float inv = 1.f/warp_sum(ex1+ex2);
      attw[w*128+lane] = ex1*inv;
      if (lane<23) attw[w*128+64+lane] = ex2*inv;
      float o = 0.f;
      for (int m=0;m<87;++m) o += attw[w*128+m]*whs[m*64+lane];
      float val = (o>0.f) ? o : expm1f(o);
      xg[(size_t)(b*87+n)*512 + hd*64 + lane] = val;
    }
  }
}

// ---------------------------------------------------------------------------
__global__ __launch_bounds__(256) void k_final(
    const float* __restrict__ xg, const float* __restrict__ ft_vec,
    const float* __restrict__ outW, const float* __restrict__ outa,
    const float* __restrict__ lxW, const float* __restrict__ lxb,
    const float* __restrict__ lpW, const float* __restrict__ lpb,
    const float* __restrict__ adj, float* __restrict__ out){
  __shared__ float whs2[176];
  __shared__ float a1s[96], a2s[96];
  const int tid = threadIdx.x;
  const int b = blockIdx.x;
  const int w = tid>>6, lane = tid&63;
  for (int item=w; item<174; item+=4){
    int ss = item>>1, c = item&1;
    const float* xr = xg + (size_t)(b*87+ss)*512;
    float a = 0.f;
    #pragma unroll
    for (int kk=0;kk<8;++kk) a += xr[kk*64+lane]*outW[(kk*64+lane)*2+c];
    a = warp_sum(a);
    if (lane==0) whs2[item] = a;
  }
  __syncthreads();
  for (int idx=tid; idx<87; idx+=256){
    a1s[idx] = whs2[idx*2]*outa[0] + whs2[idx*2+1]*outa[1];
    a2s[idx] = whs2[idx*2]*outa[2] + whs2[idx*2+1]*outa[3];
  }
  __syncthreads();
  for (int i=0;i<22;++i){
    int n = w + 4*i;
    if (n<87){
      float a1n = a1s[n];
      float x1 = a1n + a2s[lane];
      float e1 = (adj[n*87+lane]>0.f) ? (x1>0.f?x1:0.2f*x1) : -9e15f;
      float e2 = -INFINITY;
      if (lane<23){
        float x2 = a1n + a2s[64+lane];
        e2 = (adj[n*87+64+lane]>0.f) ? (x2>0.f?x2:0.2f*x2) : -9e15f;
      }
      float mx  = warp_max(fmaxf(e1,e2));
      float ex1 = expf(e1-mx);
      float ex2 = (lane<23)?expf(e2-mx):0.f;
      float inv = 1.f/warp_sum(ex1+ex2);
      float at1 = ex1*inv, at2 = ex2*inv;
      float p0 = at1*whs2[lane*2];
      float p1 = at1*whs2[lane*2+1];
      if (lane<23){ p0 += at2*whs2[(64+lane)*2]; p1 += at2*whs2[(64+lane)*2+1]; }
      float s0 = warp_sum(p0);
      float s1 = warp_sum(p1);
      float ftv = ft_vec[(size_t)(b*87+n)*64 + lane];
      float d0 = warp_sum(ftv*lxW[lane]);
      float d1 = warp_sum(ftv*lxW[64+lane]);
      float dp = warp_sum(ftv*lpW[lane]);
      if (lane==0){
        float ep  = tanhf(dp + lpb[0])*0.01f;
        float o10 = tanhf(d0 + lxb[0]);
        float o11 = tanhf(d1 + lxb[1]);
        float g0 = (s0>0.f)?s0:expm1f(s0);
        float g1 = (s1>0.f)?s1:expm1f(s1);
        float* op = out + (size_t)(b*87+n)*3;
        op[0] = ep; op[1] = g0 + o10; op[2] = g1 + o11;
      }
    }
  }
}

// ---------------------------------------------------------------------------
extern "C" void kernel_launch(void* const* d_in, const int* in_sizes, int n_in,
                              void* d_out, int out_size, void* d_ws, size_t ws_size,
                              hipStream_t stream){
  const float* text      = (const float*)d_in[0];
  const float* price     = (const float*)d_in[1];
  const float* adj       = (const float*)d_in[2];
  const float* grup_Wih  = (const float*)d_in[4];
  const float* grup_Whh  = (const float*)d_in[5];
  const float* grup_bih  = (const float*)d_in[6];
  const float* grup_bhh  = (const float*)d_in[7];
  const float* tgru_Wih  = (const float*)d_in[8];
  const float* tgru_Whh  = (const float*)d_in[9];
  const float* tgru_bih  = (const float*)d_in[10];
  const float* tgru_bhh  = (const float*)d_in[11];
  const float* grut_Wih  = (const float*)d_in[12];
  const float* grut_Whh  = (const float*)d_in[13];
  const float* grut_bih  = (const float*)d_in[14];
  const float* grut_bhh  = (const float*)d_in[15];
  const float* attnp_W1  = (const float*)d_in[16];
  const float* attnp_b1  = (const float*)d_in[17];
  const float* attnp_W2  = (const float*)d_in[18];
  const float* attnp_b2  = (const float*)d_in[19];
  const float* attnp_V   = (const float*)d_in[20];
  const float* attnp_bV  = (const float*)d_in[21];
  const float* attw_W1   = (const float*)d_in[22];
  const float* attw_b1   = (const float*)d_in[23];
  const float* attw_W2   = (const float*)d_in[24];
  const float* attw_b2   = (const float*)d_in[25];
  const float* attw_V    = (const float*)d_in[26];
  const float* attw_bV   = (const float*)d_in[27];
  const float* attnt_W1  = (const float*)d_in[28];
  const float* attnt_b1  = (const float*)d_in[29];
  const float* attnt_W2  = (const float*)d_in[30];
  const float* attnt_b2  = (const float*)d_in[31];
  const float* attnt_V   = (const float*)d_in[32];
  const float* attnt_bV  = (const float*)d_in[33];
  const float* bil_W     = (const float*)d_in[34];
  const float* bil_b     = (const float*)d_in[35];
  const float* lx_W      = (const float*)d_in[36];
  const float* lx_b      = (const float*)d_in[37];
  const float* lp_W      = (const float*)d_in[38];
  const float* lp_b      = (const float*)d_in[39];
  const float* gat_W     = (const float*)d_in[40];
  const float* gat_a     = (const float*)d_in[41];
  const float* out_W     = (const float*)d_in[42];
  const float* out_a     = (const float*)d_in[43];

  float* ws       = (float*)d_ws;
  float* xi_t     = ws;                      // 20,044,800
  float* full_t   = xi_t   + 20044800;       //  6,681,600
  float* news     = full_t + 6681600;        //    222,720
  float* x_price  = news   + 222720;         //     44,544
  float* text_vec = x_price + 44544;         //     44,544
  float* ft_vec   = text_vec + 44544;        //     44,544
  float* Wh_g     = ft_vec + 44544;          //  2,850,816
  float* a1h      = Wh_g   + 2850816;        //      5,568
  float* a2h      = a1h    + 5568;           //      5,568
  float* xg       = a2h    + 5568;           //    356,352
  float* q        = Wh_g;                    // alias (disjoint lifetime)

  k_tweet_proj<<<dim3(3,5,87),256,0,stream>>>(text, tgru_Wih, tgru_bih, xi_t);
  k_gru30<<<435,384,0,stream>>>(xi_t, tgru_Whh, tgru_bhh, attw_W1, attw_b1, full_t, q);
  k_uproj<<<435,256,0,stream>>>(full_t, q, attw_W2, attw_b2, attw_V, attw_bV, news);
  k_price<<<87,256,0,stream>>>(price, grup_Wih, grup_Whh, grup_bih, grup_bhh,
      attnp_W1, attnp_b1, attnp_W2, attnp_b2, attnp_V, attnp_bV, x_price);
  k_day<<<87,256,0,stream>>>(news, grut_Wih, grut_Whh, grut_bih, grut_bhh,
      attnt_W1, attnt_b1, attnt_W2, attnt_b2, attnt_V, attnt_bV, text_vec);
  k_bilinear<<<dim3(16,87),256,0,stream>>>(text_vec, x_price, bil_W, bil_b, ft_vec);
  k_gat_wh<<<64,256,0,stream>>>(ft_vec, gat_W, gat_a, Wh_g, a1h, a2h);
  k_gat_att<<<64,256,0,stream>>>(Wh_g, a1h, a2h, adj, xg);
  k_final<<<8,256,0,stream>>>(xg, ft_vec, out_W, out_a, lx_W, lx_b, lp_W, lp_b,
      adj, (float*)d_out);
}